// Round 7
// baseline (1079.357 us; speedup 1.0000x reference)
//
#include <hip/hip_runtime.h>
#include <cstdint>
#include <cstddef>

#define TT 20
#define BB 262144

// f64 packed weight layout (element offsets, in doubles):
//   W1H [2][10][32] @ 0     (mode0 fallback; mfma path does not read it)
//   W2T/W3P/W4T/W5T @ 640.. (mode0/fallback only)   total 4320 doubles
//
// mode1 (MFMA path) reuses the dead f64 spans for i8 digit fragments (u32):
//   B2 @ dword 1280: 2560  (l2: 32x32x32, W2 scale 2^39)   [R3/R4-proven]
//   B3 @ dword 3840: 1280  (l3: 32x32x32, W3 scale 2^38)   [R3/R4-proven]
//   B4 @ dword 5120: 1280  (l4: 32x32x32, W4 scale 2^38, cols>=16 zero) [R7: repacked from R5's 16x16]
//   B5 @ dword 6400: 1280  (l5: 32x32x32, W5 scale 2^38, cols>=6 / k>=16 zero)
//   B1 (l1 x-digit pairs) at tail of the old P2 region (now otherwise unused).
//
// 32x32 frag k-map (proven absmax=0 on l2/l3): lane l: row/col = l&31,
//   k = (l>>5)*16 + reg*4 + byte, byte0 = LSB. C/D: col=lane&31,
//   row=(reg&3)+8*(reg>>2)+4*(lane>>5); gather inverse rsel/hi_half proven.
//
// R7 fusion: layers 2-5 in ONE kernel. Key invariant: the ballot-fold gather
// leaves om (elem el's full spike mask) in ALL 64 lanes — which is exactly the
// A-operand decode input format of the next layer ((om>>sh)&0xffff). So the
// l2->l3->l4->l5 chain runs entirely in-register; P2/P3 traffic and 2 launches
// are eliminated. l4/l5 zero-padding: B4 cols 16-31 zero => m4 stays 0 there
// => om4 bits 16-31 zero => l5's half-1 A-slice zero (double-protected by B5
// k>=16 rows being zero).
#define OFF_W2T 640
#define OFF_W3P 2688
#define OFF_W4T 3712
#define OFF_W5T 4224
#define W_TOTAL 4320
#define B2_DW   1280
#define B3_DW   3840
#define B4_DW   5120
#define B5_DW   6400

// workspace layout (bytes) — same 62,949,376 B budget proven earlier.
//   Wd @ 0 (pad to 34816); P1 @ 34816: u32[TT][BB][2]; old P2 region now only
//   hosts B1 at its tail.
#define WS_MASK_BASE 34816
#define P1_BYTES (2 * (size_t)TT * BB * 4)
#define P2_OFFSET (WS_MASK_BASE + P1_BYTES)
#define P2_BYTES ((size_t)TT * BB * 4)
#define WS_NEEDED (P2_OFFSET + P2_BYTES)
#define B1_BYTES (22 * 256 * 4)                 // 22528
#define B1_OFFSET (WS_NEEDED - B1_BYTES)        // tail (dead space in mode1)

typedef __attribute__((ext_vector_type(4))) int i32x4;
typedef __attribute__((ext_vector_type(16))) int i32x16;

// l1 MFMA schedule: {iA, jA, iB, jB} (x-level, w-level per lane-half; iB<0 =>
// half B zero). Rounds: m0-1 -> c3 accL, m2-4 -> c4 accH (scale 2^-49);
// m5-6 -> c5, m7-8 -> c6 (2^-33); m9 -> c7, m10 -> c8 (2^-17).
__constant__ int SCHED[11][4] = {
  {0,3,1,2},{2,1,3,0},{0,4,1,3},{2,2,3,1},{4,0,-1,0},
  {1,4,2,3},{3,2,4,1},{2,4,3,3},{4,2,-1,0},{3,4,4,3},{4,4,-1,0}};

// digit d of the exact signed base-256 decomposition of llrint(w*scale).
__device__ inline uint32_t digit_of(double w, double scale, int d) {
  long long n = llrint(w * scale);
  int dig = 0;
  for (int i = 0; i <= d; ++i) {
    dig = (int)(signed char)((int)(n & 0xffll));
    n = (n - (long long)dig) >> 8;
  }
  return (uint32_t)(dig & 0xff);
}

__global__ void prep_weights(const float* __restrict__ W1, const float* __restrict__ W2,
                             const float* __restrict__ W3, const float* __restrict__ W4,
                             const float* __restrict__ W5, double* __restrict__ Wd, int mode) {
  int stride = blockDim.x * gridDim.x;
  int total = mode ? (7040 + 5632) : W_TOTAL;
  for (int idx = blockIdx.x * blockDim.x + threadIdx.x; idx < total; idx += stride) {
    if (mode) {
      if (idx < 640) {                       // W1H f64 (legacy slot, unused in mode1)
        int j = idx; int p = j / 320, k = (j % 320) / 32, o = j % 32;
        Wd[j] = (double)W1[(p * 32 + o) * 10 + k];
      } else if (idx < 3200) {               // B2 (32x32), scale 2^39
        int j = idx - 640;
        int r = j & 3, lane = (j >> 2) & 63, s = (j >> 8) & 1, d = j >> 9;
        int col = lane & 31, kb = s * 32 + (lane >> 5) * 16 + r * 4;
        uint32_t u = 0;
        for (int jj = 0; jj < 4; ++jj) {
          double w = (double)W2[col * 64 + kb + jj];
          u |= digit_of(w, 0x1p39, d) << (8 * jj);
        }
        ((uint32_t*)Wd)[B2_DW + j] = u;
      } else if (idx < 4480) {               // B3 (32x32), scale 2^38
        int j = idx - 3200;
        int r = j & 3, lane = (j >> 2) & 63, d = j >> 8;
        int col = lane & 31, kb = (lane >> 5) * 16 + r * 4;
        uint32_t u = 0;
        for (int jj = 0; jj < 4; ++jj) {
          double w = (double)W3[col * 32 + kb + jj];
          u |= digit_of(w, 0x1p38, d) << (8 * jj);
        }
        ((uint32_t*)Wd)[B3_DW + j] = u;
      } else if (idx < 5760) {               // B4 (32x32, cols>=16 zero), scale 2^38
        int j = idx - 4480;
        int r = j & 3, lane = (j >> 2) & 63, d = j >> 8;
        int col = lane & 31, kb = (lane >> 5) * 16 + r * 4;
        uint32_t u = 0;
        for (int jj = 0; jj < 4; ++jj) {
          int k = kb + jj;                   // always < 32
          double w = (col < 16) ? (double)W4[col * 32 + k] : 0.0;
          u |= digit_of(w, 0x1p38, d) << (8 * jj);
        }
        ((uint32_t*)Wd)[B4_DW + j] = u;
      } else if (idx < 7040) {               // B5 (32x32, cols>=6 / k>=16 zero), scale 2^38
        int j = idx - 5760;
        int r = j & 3, lane = (j >> 2) & 63, d = j >> 8;
        int col = lane & 31, kb = (lane >> 5) * 16 + r * 4;
        uint32_t u = 0;
        for (int jj = 0; jj < 4; ++jj) {
          int k = kb + jj;
          double w = (col < 6 && k < 16) ? (double)W5[col * 16 + k] : 0.0;
          u |= digit_of(w, 0x1p38, d) << (8 * jj);
        }
        ((uint32_t*)Wd)[B5_DW + j] = u;
      } else {                               // B1 (l1 32x32x32 pair frags), W1 scale 2^38
        int j = idx - 7040;
        int mg = j >> 8, rem = j & 255, lane = rem >> 2, r = rem & 3;
        int tile = mg / 11, sidx = mg % 11, half = lane >> 5;
        int jd   = half ? SCHED[sidx][3] : SCHED[sidx][1];
        int vld  = half ? (SCHED[sidx][2] >= 0) : 1;
        int o = (lane & 31) + 32 * tile;
        uint32_t u = 0;
        if (vld) {
          for (int b = 0; b < 4; ++b) {
            int k = r * 4 + b;
            if (k < 10) u |= digit_of((double)W1[o * 10 + k], 0x1p38, jd) << (8 * b);
          }
        }
        ((uint32_t*)((char*)Wd + B1_OFFSET))[mg * 256 + lane * 4 + r] = u;
      }
    } else {
      double v;
      if (idx < OFF_W2T) {
        int j = idx;            int p = j / 320, k = (j % 320) / 32, o = j % 32;
        v = (double)W1[(p * 32 + o) * 10 + k];
      } else if (idx < OFF_W3P) {
        int j = idx - OFF_W2T;  int k = j / 32, o = j % 32;
        v = (double)W2[o * 64 + k];
      } else if (idx < OFF_W4T) {
        int j = idx - OFF_W3P;  int p = j / 512, k = (j % 512) / 16, o = j % 16;
        v = (double)W3[(p * 16 + o) * 32 + k];
      } else if (idx < OFF_W5T) {
        int j = idx - OFF_W4T;  int k = j / 16, o = j % 16; v = (double)W4[o * 32 + k];
      } else {
        int j = idx - OFF_W5T;  int k = j / 6,  o = j % 6;  v = (double)W5[o * 16 + k];
      }
      Wd[idx] = v;
    }
  }
}

#define MFI(A4, B4, C16) __builtin_amdgcn_mfma_i32_32x32x32_i8((A4), (B4), (C16), 0, 0, 0)

// One out-tile of l1: leak, 11 MFMAs in 3 c-rounds, f64 reconstruction.
#define L1_TILE(MA, BASE)                                                     \
  {                                                                           \
    _Pragma("unroll") for (int r2 = 0; r2 < 16; ++r2) {                       \
      const double sub = (MA[r2] > 1.0) ? 1.0 : 0.0;                          \
      MA[r2] = fma(0.9, MA[r2], -sub);                                        \
    }                                                                         \
    i32x16 aL, aH;                                                            \
    aL = MFI(hi ? wd1 : wd0, BL[(BASE + 0) * 64 + lane], zz16);               \
    aL = MFI(hi ? wd3 : wd2, BL[(BASE + 1) * 64 + lane], aL);                 \
    aH = MFI(hi ? wd1 : wd0, BL[(BASE + 2) * 64 + lane], zz16);               \
    aH = MFI(hi ? wd3 : wd2, BL[(BASE + 3) * 64 + lane], aH);                 \
    aH = MFI(hi ? zz4 : wd4, BL[(BASE + 4) * 64 + lane], aH);                 \
    _Pragma("unroll") for (int r2 = 0; r2 < 16; ++r2) {                       \
      const int cmb = aL[r2] + (aH[r2] << 8);                                 \
      MA[r2] = fma((double)cmb, 0x1p-49, MA[r2]);                             \
    }                                                                         \
    aL = MFI(hi ? wd2 : wd1, BL[(BASE + 5) * 64 + lane], zz16);               \
    aL = MFI(hi ? wd4 : wd3, BL[(BASE + 6) * 64 + lane], aL);                 \
    aH = MFI(hi ? wd3 : wd2, BL[(BASE + 7) * 64 + lane], zz16);               \
    aH = MFI(hi ? zz4 : wd4, BL[(BASE + 8) * 64 + lane], aH);                 \
    _Pragma("unroll") for (int r2 = 0; r2 < 16; ++r2) {                       \
      const int cmb = aL[r2] + (aH[r2] << 8);                                 \
      MA[r2] = fma((double)cmb, 0x1p-33, MA[r2]);                             \
    }                                                                         \
    aL = MFI(hi ? wd4 : wd3, BL[(BASE + 9) * 64 + lane], zz16);               \
    aH = MFI(hi ? zz4 : wd4, BL[(BASE + 10) * 64 + lane], zz16);              \
    _Pragma("unroll") for (int r2 = 0; r2 < 16; ++r2) {                       \
      const int cmb = aL[r2] + (aH[r2] << 8);                                 \
      MA[r2] = fma((double)cmb, 0x1p-17, MA[r2]);                             \
    }                                                                         \
  }

// Layer 1 (10 -> 64) via i8-digit MFMA (R6-proven). One wave = 32 elems.
__global__ __launch_bounds__(256, 2) void snn_l1_mfma(const float* __restrict__ x,
                                                      const uint32_t* __restrict__ B1g,
                                                      uint32_t* __restrict__ P1) {
  __shared__ __align__(16) uint32_t Bsh[5632];
  for (int i = threadIdx.x; i < 5632; i += 256) Bsh[i] = B1g[i];
  __syncthreads();

  const int lane = threadIdx.x & 63;
  const int wave = threadIdx.x >> 6;
  const int ebase = blockIdx.x * 128 + wave * 32;
  const int el = lane & 31;
  const bool hi = lane >= 32;
  const int rsel = (el & 3) | (((el >> 3) & 3) << 2);   // proven C/D inverse
  const int hi_half = (el >> 2) & 1;
  const i32x4* __restrict__ BL = (const i32x4*)Bsh;

  double m0a[16], m1a[16];
#pragma unroll
  for (int i = 0; i < 16; ++i) { m0a[i] = 0.0; m1a[i] = 0.0; }

  float2 xf[5];
  {
    const float2* xp = (const float2*)(x + (size_t)(ebase + el) * 10);
#pragma unroll
    for (int i = 0; i < 5; ++i) xf[i] = xp[i];
  }
  uint32_t* __restrict__ dst = P1 + (size_t)(ebase + el) * 2 + (hi ? 1 : 0);

#pragma unroll 1
  for (int t = 0; t < TT; ++t) {
    float xv[10];
#pragma unroll
    for (int i = 0; i < 5; ++i) { xv[2 * i] = xf[i].x; xv[2 * i + 1] = xf[i].y; }
    if (t + 1 < TT) {
      const float2* xn = (const float2*)(x + ((size_t)(t + 1) * BB + ebase + el) * 10);
#pragma unroll
      for (int i = 0; i < 5; ++i) xf[i] = xn[i];
    }

    // x digits: X = x*2^35 = nh*2^16 + nl exactly (two rint splits), then 5
    // signed base-256 digits packed bytewise into wd0..wd4.
    i32x4 wd0 = {0,0,0,0}, wd1 = {0,0,0,0}, wd2 = {0,0,0,0},
          wd3 = {0,0,0,0}, wd4 = {0,0,0,0};
#pragma unroll
    for (int k = 0; k < 10; ++k) {
      const double xd = (double)xv[k];
      const double nhf = rint(xd * 0x1p19);
      int nh = (int)nhf;
      const double r = fma(-nhf, 0x1p-19, xd);          // exact residual
      const int nl = (int)rint(r * 0x1p35);             // |nl| <= 2^15
      const int d0 = ((nl + 128) & 255) - 128;
      const int rem = (nl - d0) >> 8;                   // [-128, 128]
      const int carry = (rem + 128) >> 8;               // 1 iff rem == 128
      const int d1 = rem - (carry << 8);
      nh += carry;
      const int d2 = ((nh + 128) & 255) - 128;
      const int n2 = (nh - d2) >> 8;
      const int d3 = ((n2 + 128) & 255) - 128;
      const int d4 = (n2 - d3) >> 8;
      const int q = k >> 2, sh8 = (k & 3) * 8;
      wd0[q] |= (d0 & 255) << sh8;
      wd1[q] |= (d1 & 255) << sh8;
      wd2[q] |= (d2 & 255) << sh8;
      wd3[q] |= (d3 & 255) << sh8;
      wd4[q] |= (d4 & 255) << sh8;
    }
    const i32x4 zz4 = {0, 0, 0, 0};
    const i32x16 zz16 = {0,0,0,0,0,0,0,0,0,0,0,0,0,0,0,0};

    L1_TILE(m0a, 0);                                    // outputs 0..31
    unsigned long long sel0 = 0ull;
#pragma unroll
    for (int r2 = 0; r2 < 16; ++r2) {
      const unsigned long long b = __ballot(m0a[r2] > 1.0);
      sel0 = (r2 == 0) ? b : ((rsel == r2) ? b : sel0);
    }

    L1_TILE(m1a, 11);                                   // outputs 32..63
    unsigned long long sel1 = 0ull;
#pragma unroll
    for (int r2 = 0; r2 < 16; ++r2) {
      const unsigned long long b = __ballot(m1a[r2] > 1.0);
      sel1 = (r2 == 0) ? b : ((rsel == r2) ? b : sel1);
    }

    const unsigned long long merged = hi ? sel1 : sel0;
    const uint32_t om = hi_half ? (uint32_t)(merged >> 32) : (uint32_t)merged;
    dst[(size_t)t * BB * 2] = om;                       // full-wave coalesced
  }
}

// One fused-layer step (single k-slice, 5 digit-MFMAs, scale 2^38):
// decode OMIN -> MFMA vs frags at BL[BX..] -> update MARR -> gather OMOUT.
#define LSTEP(MARR, BX, OMIN, OMOUT)                                          \
  {                                                                           \
    const uint32_t bl_ = ((OMIN) >> sh) & 0xffffu;                            \
    i32x4 a_;                                                                 \
    _Pragma("unroll") for (int r = 0; r < 4; ++r)                             \
      a_[r] = (int)((((bl_ >> (4 * r)) & 15u) * 0x00204081u) & 0x01010101u);  \
    i32x16 Slo_, Shi_, Cw_;                                                   \
    Slo_ = MFI(a_, BL[(BX) + lane], zz16);                                    \
    Cw_  = MFI(a_, BL[(BX) + 64 + lane], zz16);                               \
    Slo_ += Cw_ << 8;                                                         \
    Cw_  = MFI(a_, BL[(BX) + 128 + lane], zz16);                              \
    Slo_ += Cw_ << 16;                                                        \
    Shi_ = MFI(a_, BL[(BX) + 192 + lane], zz16);                              \
    Cw_  = MFI(a_, BL[(BX) + 256 + lane], zz16);                              \
    Shi_ += Cw_ << 8;                                                         \
    unsigned long long sel_ = 0ull;                                           \
    _Pragma("unroll") for (int i = 0; i < 16; ++i) {                          \
      const double sub = (MARR[i] > 1.0) ? 1.0 : 0.0;                         \
      double md = fma(0.9, MARR[i], -sub);                                    \
      md = fma((double)Slo_[i], 0x1p-38, md);                                 \
      md = fma((double)Shi_[i], 0x1p-14, md);                                 \
      MARR[i] = md;                                                           \
      const unsigned long long b = __ballot(md > 1.0);                        \
      sel_ = (i == 0) ? b : ((rsel == i) ? b : sel_);                         \
    }                                                                         \
    OMOUT = hi_half ? (uint32_t)(sel_ >> 32) : (uint32_t)sel_;                \
  }

// Layers 2+3+4+5 fused. One wave = 32 elems through the whole back-half.
// The gather leaves each elem's mask in ALL 64 lanes -> feeds next decode.
__global__ __launch_bounds__(256, 2) void snn_l2345(const double* __restrict__ Wd,
                                                    const uint32_t* __restrict__ P1,
                                                    float* __restrict__ out) {
  __shared__ __align__(16) uint32_t Bsh[6400];
  {
    const uint32_t* __restrict__ Bg = (const uint32_t*)Wd;
    for (int i = threadIdx.x; i < 2560; i += 256) Bsh[i] = Bg[B2_DW + i];
    for (int i = threadIdx.x; i < 1280; i += 256) {
      Bsh[2560 + i] = Bg[B3_DW + i];
      Bsh[3840 + i] = Bg[B4_DW + i];
      Bsh[5120 + i] = Bg[B5_DW + i];
    }
  }
  __syncthreads();

  const int lane = threadIdx.x & 63;
  const int wave = threadIdx.x >> 6;
  const int ebase = blockIdx.x * 128 + wave * 32;
  const int sh = (lane >> 5) * 16;                      // k-half select
  const int el = lane & 31;
  const uint2* __restrict__ src = (const uint2*)P1 + (ebase + el);
  const i32x4* __restrict__ BL = (const i32x4*)Bsh;     // B2@0 B3@640 B4@960 B5@1280

  const int rsel = (el & 3) | (((el >> 3) & 3) << 2);   // proven C/D inverse
  const int hi_half = (el >> 2) & 1;

  double m2[16], m3[16], m4[16], m5[16];
#pragma unroll
  for (int i = 0; i < 16; ++i) { m2[i] = 0.0; m3[i] = 0.0; m4[i] = 0.0; m5[i] = 0.0; }

  const i32x16 zz16 = {0,0,0,0,0,0,0,0,0,0,0,0,0,0,0,0};

  uint2 vm = src[0];
#pragma unroll 1
  for (int t = 0; t < TT; ++t) {
    const uint2 v = vm;
    if (t + 1 < TT) vm = src[(size_t)(t + 1) * BB];     // prefetch next t

    // ---- l2 (64 -> 32): two k-slices, scale 2^39 (proven verbatim) ----
    uint32_t om2;
    {
      const uint32_t bl0 = (v.x >> sh) & 0xffffu;
      const uint32_t bl1 = (v.y >> sh) & 0xffffu;
      i32x4 a0, a1;
#pragma unroll
      for (int r = 0; r < 4; ++r) {
        a0[r] = (int)((((bl0 >> (4 * r)) & 15u) * 0x00204081u) & 0x01010101u);
        a1[r] = (int)((((bl1 >> (4 * r)) & 15u) * 0x00204081u) & 0x01010101u);
      }
      i32x16 Slo, Shi, Cw;
      Slo = MFI(a0, BL[lane],       zz16);
      Slo = MFI(a1, BL[64 + lane],  Slo);
      Cw  = MFI(a0, BL[128 + lane], zz16);
      Cw  = MFI(a1, BL[192 + lane], Cw);
      Slo += Cw << 8;
      Cw  = MFI(a0, BL[256 + lane], zz16);
      Cw  = MFI(a1, BL[320 + lane], Cw);
      Slo += Cw << 16;
      Shi = MFI(a0, BL[384 + lane], zz16);
      Shi = MFI(a1, BL[448 + lane], Shi);
      Cw  = MFI(a0, BL[512 + lane], zz16);
      Cw  = MFI(a1, BL[576 + lane], Cw);
      Shi += Cw << 8;

      unsigned long long sel = 0ull;
#pragma unroll
      for (int i = 0; i < 16; ++i) {
        const double sub = (m2[i] > 1.0) ? 1.0 : 0.0;
        double md = fma(0.9, m2[i], -sub);
        md = fma((double)Slo[i], 0x1p-39, md);
        md = fma((double)Shi[i], 0x1p-15, md);
        m2[i] = md;
        const unsigned long long b = __ballot(md > 1.0);
        sel = (i == 0) ? b : ((rsel == i) ? b : sel);
      }
      om2 = hi_half ? (uint32_t)(sel >> 32) : (uint32_t)sel;
    }

    // ---- l3 (32 -> 32), l4 (32 -> 16 padded), l5 (16 -> 6 padded) ----
    uint32_t om3, om4, om5;
    LSTEP(m3, 640,  om2, om3);
    LSTEP(m4, 960,  om3, om4);
    LSTEP(m5, 1280, om4, om5);

    if (lane < 32) {
      float* op = out + ((size_t)t * BB + ebase + el) * 6;
      ((float2*)op)[0] = make_float2((om5 & 1u)  ? 1.0f : 0.0f,
                                     (om5 & 2u)  ? 1.0f : 0.0f);
      ((float2*)op)[1] = make_float2((om5 & 4u)  ? 1.0f : 0.0f,
                                     (om5 & 8u)  ? 1.0f : 0.0f);
      ((float2*)op)[2] = make_float2((om5 & 16u) ? 1.0f : 0.0f,
                                     (om5 & 32u) ? 1.0f : 0.0f);
    }
  }
}

// ---------------- fallback: monolithic kernel (ws too small; f64 layout) ----------------

__global__ __launch_bounds__(256, 1) void snn_f64(const float* __restrict__ x,
                                                  const double* __restrict__ Wd,
                                                  float* __restrict__ out) {
  const int e = blockIdx.x * blockDim.x + threadIdx.x;

  double m1[64], m2[32], m3[32], m4[16], m5[6];
#pragma unroll
  for (int o = 0; o < 64; ++o) m1[o] = 0.0;
#pragma unroll
  for (int o = 0; o < 32; ++o) m2[o] = 0.0;
#pragma unroll
  for (int o = 0; o < 32; ++o) m3[o] = 0.0;
#pragma unroll
  for (int o = 0; o < 16; ++o) m4[o] = 0.0;
#pragma unroll
  for (int o = 0; o < 6; ++o) m5[o] = 0.0;

#pragma unroll 1
  for (int t = 0; t < TT; ++t) {
    const float* xp = x + ((size_t)t * BB + e) * 10;
    float xv[10];
#pragma unroll
    for (int i = 0; i < 5; ++i) {
      float2 f = ((const float2*)xp)[i];
      xv[2 * i] = f.x; xv[2 * i + 1] = f.y;
    }
#pragma unroll
    for (int o = 0; o < 64; ++o) {
      double sub = (m1[o] > 1.0) ? 1.0 : 0.0;
      m1[o] = 0.9 * m1[o] - sub;
    }
#pragma unroll
    for (int p = 0; p < 2; ++p) {
#pragma unroll
      for (int k = 0; k < 10; ++k) {
        double s = (double)xv[k];
        const double* col = Wd + p * 320 + k * 32;
#pragma unroll
        for (int o = 0; o < 32; ++o) m1[p * 32 + o] = fma(s, col[o], m1[p * 32 + o]);
      }
    }
    unsigned long long msk1 = 0ull;
#pragma unroll
    for (int o = 0; o < 64; ++o) msk1 |= (m1[o] > 1.0) ? (1ull << o) : 0ull;

#pragma unroll
    for (int o = 0; o < 32; ++o) {
      double sub = (m2[o] > 1.0) ? 1.0 : 0.0;
      m2[o] = 0.9 * m2[o] - sub;
    }
    {
      unsigned long long b = msk1;
      const double* col = Wd + OFF_W2T;
      for (int k = 0; k < 64; ++k) {
        double s = (double)(unsigned int)(b & 1ull);
        b >>= 1;
#pragma unroll
        for (int o = 0; o < 32; ++o) m2[o] = fma(s, col[o], m2[o]);
        col += 32;
      }
    }
    unsigned int msk2 = 0u;
#pragma unroll
    for (int o = 0; o < 32; ++o) msk2 |= (m2[o] > 1.0) ? (1u << o) : 0u;

#pragma unroll
    for (int o = 0; o < 32; ++o) {
      double sub = (m3[o] > 1.0) ? 1.0 : 0.0;
      m3[o] = 0.9 * m3[o] - sub;
    }
#pragma unroll
    for (int p = 0; p < 2; ++p) {
      unsigned int b = msk2;
      const double* col = Wd + OFF_W3P + p * 512;
      for (int k = 0; k < 32; ++k) {
        double s = (double)(b & 1u);
        b >>= 1;
#pragma unroll
        for (int o = 0; o < 16; ++o) m3[p * 16 + o] = fma(s, col[o], m3[p * 16 + o]);
        col += 16;
      }
    }
    unsigned int msk3 = 0u;
#pragma unroll
    for (int o = 0; o < 32; ++o) msk3 |= (m3[o] > 1.0) ? (1u << o) : 0u;

#pragma unroll
    for (int o = 0; o < 16; ++o) {
      double sub = (m4[o] > 1.0) ? 1.0 : 0.0;
      m4[o] = 0.9 * m4[o] - sub;
    }
    {
      unsigned int b = msk3;
      const double* col = Wd + OFF_W4T;
      for (int k = 0; k < 32; ++k) {
        double s = (double)(b & 1u);
        b >>= 1;
#pragma unroll
        for (int o = 0; o < 16; ++o) m4[o] = fma(s, col[o], m4[o]);
        col += 16;
      }
    }
    unsigned int msk4 = 0u;
#pragma unroll
    for (int o = 0; o < 16; ++o) msk4 |= (m4[o] > 1.0) ? (1u << o) : 0u;

#pragma unroll
    for (int o = 0; o < 6; ++o) {
      double sub = (m5[o] > 1.0) ? 1.0 : 0.0;
      m5[o] = 0.9 * m5[o] - sub;
    }
    {
      unsigned int b = msk4;
      const double* col = Wd + OFF_W5T;
      for (int k = 0; k < 16; ++k) {
        double s = (double)(b & 1u);
        b >>= 1;
#pragma unroll
        for (int o = 0; o < 6; ++o) m5[o] = fma(s, col[o], m5[o]);
        col += 6;
      }
    }

    float ov[6];
#pragma unroll
    for (int o = 0; o < 6; ++o) ov[o] = (m5[o] > 1.0) ? 1.0f : 0.0f;
    float* op = out + ((size_t)t * BB + e) * 6;
    ((float2*)op)[0] = make_float2(ov[0], ov[1]);
    ((float2*)op)[1] = make_float2(ov[2], ov[3]);
    ((float2*)op)[2] = make_float2(ov[4], ov[5]);
  }
}

extern "C" void kernel_launch(void* const* d_in, const int* in_sizes, int n_in,
                              void* d_out, int out_size, void* d_ws, size_t ws_size,
                              hipStream_t stream) {
  const float* x  = (const float*)d_in[0];
  const float* W1 = (const float*)d_in[1];
  const float* W2 = (const float*)d_in[2];
  const float* W3 = (const float*)d_in[3];
  const float* W4 = (const float*)d_in[4];
  const float* W5 = (const float*)d_in[5];
  float* out = (float*)d_out;
  double* Wd = (double*)d_ws;

  const int mode = (ws_size >= WS_NEEDED) ? 1 : 0;
  prep_weights<<<50, 256, 0, stream>>>(W1, W2, W3, W4, W5, Wd, mode);

  if (mode) {
    char* base = (char*)d_ws;
    uint32_t* P1 = (uint32_t*)(base + WS_MASK_BASE);   // u32[TT][BB][2]
    const uint32_t* B1 = (const uint32_t*)(base + B1_OFFSET);
    snn_l1_mfma<<<2048, 256, 0, stream>>>(x, B1, P1);
    snn_l2345<<<2048, 256, 0, stream>>>(Wd, (const uint32_t*)P1, out);
  } else {
    snn_f64<<<BB / 256, 256, 0, stream>>>(x, Wd, out);
  }
}

// Round 8
// 1052.181 us; speedup vs baseline: 1.0258x; 1.0258x over previous
//
#include <hip/hip_runtime.h>
#include <cstdint>
#include <cstddef>

#define TT 20
#define BB 262144

// f64 packed weight layout (element offsets, in doubles):
//   W1H [2][10][32] @ 0     (mode0 fallback; mfma path does not read it)
//   W2T/W3P/W4T/W5T @ 640.. (mode0/fallback only)   total 4320 doubles
//
// mode1 (MFMA path) reuses the dead f64 spans for i8 digit fragments (u32):
//   B2 @ dword 1280: 2560  (l2: 32x32x32, W2 scale 2^39)   [R3/R4-proven]
//   B3 @ dword 3840: 1280  (l3: 32x32x32, W3 scale 2^38)   [R3/R4-proven]
//   B4 @ dword 5120: 1280  (l4: 32x32x32, W4 scale 2^38, cols>=16 zero)
//   B5 @ dword 6400: 1280  (l5: 32x32x32, W5 scale 2^38, cols>=6 / k>=16 zero)
//   B1 (l1 x-digit pairs) at tail of the old P2 region.
//
// 32x32 frag k-map (proven absmax=0): lane l: row/col = l&31,
//   k = (l>>5)*16 + reg*4 + byte, byte0 = LSB. C/D: col=lane&31,
//   row=(reg&3)+8*(reg>>2)+4*(lane>>5); gather inverse rsel/hi_half proven.
//
// R8: R7's fused l2345 spilled (WRITE 241 MB vs 126 algorithmic) because
// (256,2) caps the unified file at 256 regs while live set ~250 peaked over.
// Fix = launch_bounds (256,1) (cap 512; HW occupancy set by actual use, same
// 2 waves/SIMD) + LSTEP re-chained to 2 live i32x16 accumulators (was 3).
#define OFF_W2T 640
#define OFF_W3P 2688
#define OFF_W4T 3712
#define OFF_W5T 4224
#define W_TOTAL 4320
#define B2_DW   1280
#define B3_DW   3840
#define B4_DW   5120
#define B5_DW   6400

// workspace layout (bytes) — same 62,949,376 B budget proven earlier.
#define WS_MASK_BASE 34816
#define P1_BYTES (2 * (size_t)TT * BB * 4)
#define P2_OFFSET (WS_MASK_BASE + P1_BYTES)
#define P2_BYTES ((size_t)TT * BB * 4)
#define WS_NEEDED (P2_OFFSET + P2_BYTES)
#define B1_BYTES (22 * 256 * 4)                 // 22528
#define B1_OFFSET (WS_NEEDED - B1_BYTES)        // tail (dead space in mode1)

typedef __attribute__((ext_vector_type(4))) int i32x4;
typedef __attribute__((ext_vector_type(16))) int i32x16;

// l1 MFMA schedule: {iA, jA, iB, jB} (x-level, w-level per lane-half; iB<0 =>
// half B zero). Rounds: m0-1 -> c3 accL, m2-4 -> c4 accH (scale 2^-49);
// m5-6 -> c5, m7-8 -> c6 (2^-33); m9 -> c7, m10 -> c8 (2^-17).
__constant__ int SCHED[11][4] = {
  {0,3,1,2},{2,1,3,0},{0,4,1,3},{2,2,3,1},{4,0,-1,0},
  {1,4,2,3},{3,2,4,1},{2,4,3,3},{4,2,-1,0},{3,4,4,3},{4,4,-1,0}};

// digit d of the exact signed base-256 decomposition of llrint(w*scale).
__device__ inline uint32_t digit_of(double w, double scale, int d) {
  long long n = llrint(w * scale);
  int dig = 0;
  for (int i = 0; i <= d; ++i) {
    dig = (int)(signed char)((int)(n & 0xffll));
    n = (n - (long long)dig) >> 8;
  }
  return (uint32_t)(dig & 0xff);
}

__global__ void prep_weights(const float* __restrict__ W1, const float* __restrict__ W2,
                             const float* __restrict__ W3, const float* __restrict__ W4,
                             const float* __restrict__ W5, double* __restrict__ Wd, int mode) {
  int stride = blockDim.x * gridDim.x;
  int total = mode ? (7040 + 5632) : W_TOTAL;
  for (int idx = blockIdx.x * blockDim.x + threadIdx.x; idx < total; idx += stride) {
    if (mode) {
      if (idx < 640) {                       // W1H f64 (legacy slot, unused in mode1)
        int j = idx; int p = j / 320, k = (j % 320) / 32, o = j % 32;
        Wd[j] = (double)W1[(p * 32 + o) * 10 + k];
      } else if (idx < 3200) {               // B2 (32x32), scale 2^39
        int j = idx - 640;
        int r = j & 3, lane = (j >> 2) & 63, s = (j >> 8) & 1, d = j >> 9;
        int col = lane & 31, kb = s * 32 + (lane >> 5) * 16 + r * 4;
        uint32_t u = 0;
        for (int jj = 0; jj < 4; ++jj) {
          double w = (double)W2[col * 64 + kb + jj];
          u |= digit_of(w, 0x1p39, d) << (8 * jj);
        }
        ((uint32_t*)Wd)[B2_DW + j] = u;
      } else if (idx < 4480) {               // B3 (32x32), scale 2^38
        int j = idx - 3200;
        int r = j & 3, lane = (j >> 2) & 63, d = j >> 8;
        int col = lane & 31, kb = (lane >> 5) * 16 + r * 4;
        uint32_t u = 0;
        for (int jj = 0; jj < 4; ++jj) {
          double w = (double)W3[col * 32 + kb + jj];
          u |= digit_of(w, 0x1p38, d) << (8 * jj);
        }
        ((uint32_t*)Wd)[B3_DW + j] = u;
      } else if (idx < 5760) {               // B4 (32x32, cols>=16 zero), scale 2^38
        int j = idx - 4480;
        int r = j & 3, lane = (j >> 2) & 63, d = j >> 8;
        int col = lane & 31, kb = (lane >> 5) * 16 + r * 4;
        uint32_t u = 0;
        for (int jj = 0; jj < 4; ++jj) {
          int k = kb + jj;                   // always < 32
          double w = (col < 16) ? (double)W4[col * 32 + k] : 0.0;
          u |= digit_of(w, 0x1p38, d) << (8 * jj);
        }
        ((uint32_t*)Wd)[B4_DW + j] = u;
      } else if (idx < 7040) {               // B5 (32x32, cols>=6 / k>=16 zero), scale 2^38
        int j = idx - 5760;
        int r = j & 3, lane = (j >> 2) & 63, d = j >> 8;
        int col = lane & 31, kb = (lane >> 5) * 16 + r * 4;
        uint32_t u = 0;
        for (int jj = 0; jj < 4; ++jj) {
          int k = kb + jj;
          double w = (col < 6 && k < 16) ? (double)W5[col * 16 + k] : 0.0;
          u |= digit_of(w, 0x1p38, d) << (8 * jj);
        }
        ((uint32_t*)Wd)[B5_DW + j] = u;
      } else {                               // B1 (l1 32x32x32 pair frags), W1 scale 2^38
        int j = idx - 7040;
        int mg = j >> 8, rem = j & 255, lane = rem >> 2, r = rem & 3;
        int tile = mg / 11, sidx = mg % 11, half = lane >> 5;
        int jd   = half ? SCHED[sidx][3] : SCHED[sidx][1];
        int vld  = half ? (SCHED[sidx][2] >= 0) : 1;
        int o = (lane & 31) + 32 * tile;
        uint32_t u = 0;
        if (vld) {
          for (int b = 0; b < 4; ++b) {
            int k = r * 4 + b;
            if (k < 10) u |= digit_of((double)W1[o * 10 + k], 0x1p38, jd) << (8 * b);
          }
        }
        ((uint32_t*)((char*)Wd + B1_OFFSET))[mg * 256 + lane * 4 + r] = u;
      }
    } else {
      double v;
      if (idx < OFF_W2T) {
        int j = idx;            int p = j / 320, k = (j % 320) / 32, o = j % 32;
        v = (double)W1[(p * 32 + o) * 10 + k];
      } else if (idx < OFF_W3P) {
        int j = idx - OFF_W2T;  int k = j / 32, o = j % 32;
        v = (double)W2[o * 64 + k];
      } else if (idx < OFF_W4T) {
        int j = idx - OFF_W3P;  int p = j / 512, k = (j % 512) / 16, o = j % 16;
        v = (double)W3[(p * 16 + o) * 32 + k];
      } else if (idx < OFF_W5T) {
        int j = idx - OFF_W4T;  int k = j / 16, o = j % 16; v = (double)W4[o * 32 + k];
      } else {
        int j = idx - OFF_W5T;  int k = j / 6,  o = j % 6;  v = (double)W5[o * 16 + k];
      }
      Wd[idx] = v;
    }
  }
}

#define MFI(A4, B4, C16) __builtin_amdgcn_mfma_i32_32x32x32_i8((A4), (B4), (C16), 0, 0, 0)

// One out-tile of l1: leak, 11 MFMAs in 3 c-rounds, f64 reconstruction.
#define L1_TILE(MA, BASE)                                                     \
  {                                                                           \
    _Pragma("unroll") for (int r2 = 0; r2 < 16; ++r2) {                       \
      const double sub = (MA[r2] > 1.0) ? 1.0 : 0.0;                          \
      MA[r2] = fma(0.9, MA[r2], -sub);                                        \
    }                                                                         \
    i32x16 aL, aH;                                                            \
    aL = MFI(hi ? wd1 : wd0, BL[(BASE + 0) * 64 + lane], zz16);               \
    aL = MFI(hi ? wd3 : wd2, BL[(BASE + 1) * 64 + lane], aL);                 \
    aH = MFI(hi ? wd1 : wd0, BL[(BASE + 2) * 64 + lane], zz16);               \
    aH = MFI(hi ? wd3 : wd2, BL[(BASE + 3) * 64 + lane], aH);                 \
    aH = MFI(hi ? zz4 : wd4, BL[(BASE + 4) * 64 + lane], aH);                 \
    _Pragma("unroll") for (int r2 = 0; r2 < 16; ++r2) {                       \
      const int cmb = aL[r2] + (aH[r2] << 8);                                 \
      MA[r2] = fma((double)cmb, 0x1p-49, MA[r2]);                             \
    }                                                                         \
    aL = MFI(hi ? wd2 : wd1, BL[(BASE + 5) * 64 + lane], zz16);               \
    aL = MFI(hi ? wd4 : wd3, BL[(BASE + 6) * 64 + lane], aL);                 \
    aH = MFI(hi ? wd3 : wd2, BL[(BASE + 7) * 64 + lane], zz16);               \
    aH = MFI(hi ? zz4 : wd4, BL[(BASE + 8) * 64 + lane], aH);                 \
    _Pragma("unroll") for (int r2 = 0; r2 < 16; ++r2) {                       \
      const int cmb = aL[r2] + (aH[r2] << 8);                                 \
      MA[r2] = fma((double)cmb, 0x1p-33, MA[r2]);                             \
    }                                                                         \
    aL = MFI(hi ? wd4 : wd3, BL[(BASE + 9) * 64 + lane], zz16);               \
    aH = MFI(hi ? zz4 : wd4, BL[(BASE + 10) * 64 + lane], zz16);              \
    _Pragma("unroll") for (int r2 = 0; r2 < 16; ++r2) {                       \
      const int cmb = aL[r2] + (aH[r2] << 8);                                 \
      MA[r2] = fma((double)cmb, 0x1p-17, MA[r2]);                             \
    }                                                                         \
  }

// Layer 1 (10 -> 64) via i8-digit MFMA (R6-proven). One wave = 32 elems.
__global__ __launch_bounds__(256, 2) void snn_l1_mfma(const float* __restrict__ x,
                                                      const uint32_t* __restrict__ B1g,
                                                      uint32_t* __restrict__ P1) {
  __shared__ __align__(16) uint32_t Bsh[5632];
  for (int i = threadIdx.x; i < 5632; i += 256) Bsh[i] = B1g[i];
  __syncthreads();

  const int lane = threadIdx.x & 63;
  const int wave = threadIdx.x >> 6;
  const int ebase = blockIdx.x * 128 + wave * 32;
  const int el = lane & 31;
  const bool hi = lane >= 32;
  const int rsel = (el & 3) | (((el >> 3) & 3) << 2);   // proven C/D inverse
  const int hi_half = (el >> 2) & 1;
  const i32x4* __restrict__ BL = (const i32x4*)Bsh;

  double m0a[16], m1a[16];
#pragma unroll
  for (int i = 0; i < 16; ++i) { m0a[i] = 0.0; m1a[i] = 0.0; }

  float2 xf[5];
  {
    const float2* xp = (const float2*)(x + (size_t)(ebase + el) * 10);
#pragma unroll
    for (int i = 0; i < 5; ++i) xf[i] = xp[i];
  }
  uint32_t* __restrict__ dst = P1 + (size_t)(ebase + el) * 2 + (hi ? 1 : 0);

#pragma unroll 1
  for (int t = 0; t < TT; ++t) {
    float xv[10];
#pragma unroll
    for (int i = 0; i < 5; ++i) { xv[2 * i] = xf[i].x; xv[2 * i + 1] = xf[i].y; }
    if (t + 1 < TT) {
      const float2* xn = (const float2*)(x + ((size_t)(t + 1) * BB + ebase + el) * 10);
#pragma unroll
      for (int i = 0; i < 5; ++i) xf[i] = xn[i];
    }

    // x digits: X = x*2^35 = nh*2^16 + nl exactly (two rint splits), then 5
    // signed base-256 digits packed bytewise into wd0..wd4.
    i32x4 wd0 = {0,0,0,0}, wd1 = {0,0,0,0}, wd2 = {0,0,0,0},
          wd3 = {0,0,0,0}, wd4 = {0,0,0,0};
#pragma unroll
    for (int k = 0; k < 10; ++k) {
      const double xd = (double)xv[k];
      const double nhf = rint(xd * 0x1p19);
      int nh = (int)nhf;
      const double r = fma(-nhf, 0x1p-19, xd);          // exact residual
      const int nl = (int)rint(r * 0x1p35);             // |nl| <= 2^15
      const int d0 = ((nl + 128) & 255) - 128;
      const int rem = (nl - d0) >> 8;                   // [-128, 128]
      const int carry = (rem + 128) >> 8;               // 1 iff rem == 128
      const int d1 = rem - (carry << 8);
      nh += carry;
      const int d2 = ((nh + 128) & 255) - 128;
      const int n2 = (nh - d2) >> 8;
      const int d3 = ((n2 + 128) & 255) - 128;
      const int d4 = (n2 - d3) >> 8;
      const int q = k >> 2, sh8 = (k & 3) * 8;
      wd0[q] |= (d0 & 255) << sh8;
      wd1[q] |= (d1 & 255) << sh8;
      wd2[q] |= (d2 & 255) << sh8;
      wd3[q] |= (d3 & 255) << sh8;
      wd4[q] |= (d4 & 255) << sh8;
    }
    const i32x4 zz4 = {0, 0, 0, 0};
    const i32x16 zz16 = {0,0,0,0,0,0,0,0,0,0,0,0,0,0,0,0};

    L1_TILE(m0a, 0);                                    // outputs 0..31
    unsigned long long sel0 = 0ull;
#pragma unroll
    for (int r2 = 0; r2 < 16; ++r2) {
      const unsigned long long b = __ballot(m0a[r2] > 1.0);
      sel0 = (r2 == 0) ? b : ((rsel == r2) ? b : sel0);
    }

    L1_TILE(m1a, 11);                                   // outputs 32..63
    unsigned long long sel1 = 0ull;
#pragma unroll
    for (int r2 = 0; r2 < 16; ++r2) {
      const unsigned long long b = __ballot(m1a[r2] > 1.0);
      sel1 = (r2 == 0) ? b : ((rsel == r2) ? b : sel1);
    }

    const unsigned long long merged = hi ? sel1 : sel0;
    const uint32_t om = hi_half ? (uint32_t)(merged >> 32) : (uint32_t)merged;
    dst[(size_t)t * BB * 2] = om;                       // full-wave coalesced
  }
}

// One fused-layer step (single k-slice, 5 digit-MFMAs, scale 2^38):
// decode OMIN -> MFMA vs frags at BL[BX..] -> update MARR -> gather OMOUT.
// R8: only 2 i32x16 live at once (Acc + Cw), digit groups folded pairwise.
#define LSTEP(MARR, BX, OMIN, OMOUT)                                          \
  {                                                                           \
    const uint32_t bl_ = ((OMIN) >> sh) & 0xffffu;                            \
    i32x4 a_;                                                                 \
    _Pragma("unroll") for (int r = 0; r < 4; ++r)                             \
      a_[r] = (int)((((bl_ >> (4 * r)) & 15u) * 0x00204081u) & 0x01010101u);  \
    i32x16 Acc_, Cw_;                                                         \
    Acc_ = MFI(a_, BL[(BX) + lane], zz16);                                    \
    Cw_  = MFI(a_, BL[(BX) + 64 + lane], zz16);                               \
    Acc_ += Cw_ << 8;                                                         \
    Cw_  = MFI(a_, BL[(BX) + 128 + lane], zz16);                              \
    Acc_ += Cw_ << 16;                                                        \
    _Pragma("unroll") for (int i = 0; i < 16; ++i) {                          \
      const double sub = (MARR[i] > 1.0) ? 1.0 : 0.0;                         \
      double md = fma(0.9, MARR[i], -sub);                                    \
      MARR[i] = fma((double)Acc_[i], 0x1p-38, md);                            \
    }                                                                         \
    Acc_ = MFI(a_, BL[(BX) + 192 + lane], zz16);                              \
    Cw_  = MFI(a_, BL[(BX) + 256 + lane], zz16);                              \
    Acc_ += Cw_ << 8;                                                         \
    unsigned long long sel_ = 0ull;                                           \
    _Pragma("unroll") for (int i = 0; i < 16; ++i) {                          \
      const double md = fma((double)Acc_[i], 0x1p-14, MARR[i]);               \
      MARR[i] = md;                                                           \
      const unsigned long long b = __ballot(md > 1.0);                        \
      sel_ = (i == 0) ? b : ((rsel == i) ? b : sel_);                         \
    }                                                                         \
    OMOUT = hi_half ? (uint32_t)(sel_ >> 32) : (uint32_t)sel_;                \
  }

// Layers 2+3+4+5 fused. One wave = 32 elems through the whole back-half.
// The gather leaves each elem's mask in ALL 64 lanes -> feeds next decode.
// launch_bounds (256,1): unified-file cap 512 regs; actual use ~250 -> HW
// still grants 2 waves/SIMD, but NO spill (R7 at (256,2) spilled 115 MB/dir).
__global__ __launch_bounds__(256, 1) void snn_l2345(const double* __restrict__ Wd,
                                                    const uint32_t* __restrict__ P1,
                                                    float* __restrict__ out) {
  __shared__ __align__(16) uint32_t Bsh[6400];
  {
    const uint32_t* __restrict__ Bg = (const uint32_t*)Wd;
    for (int i = threadIdx.x; i < 2560; i += 256) Bsh[i] = Bg[B2_DW + i];
    for (int i = threadIdx.x; i < 1280; i += 256) {
      Bsh[2560 + i] = Bg[B3_DW + i];
      Bsh[3840 + i] = Bg[B4_DW + i];
      Bsh[5120 + i] = Bg[B5_DW + i];
    }
  }
  __syncthreads();

  const int lane = threadIdx.x & 63;
  const int wave = threadIdx.x >> 6;
  const int ebase = blockIdx.x * 128 + wave * 32;
  const int sh = (lane >> 5) * 16;                      // k-half select
  const int el = lane & 31;
  const uint2* __restrict__ src = (const uint2*)P1 + (ebase + el);
  const i32x4* __restrict__ BL = (const i32x4*)Bsh;     // B2@0 B3@640 B4@960 B5@1280

  const int rsel = (el & 3) | (((el >> 3) & 3) << 2);   // proven C/D inverse
  const int hi_half = (el >> 2) & 1;

  double m2[16], m3[16], m4[16], m5[16];
#pragma unroll
  for (int i = 0; i < 16; ++i) { m2[i] = 0.0; m3[i] = 0.0; m4[i] = 0.0; m5[i] = 0.0; }

  const i32x16 zz16 = {0,0,0,0,0,0,0,0,0,0,0,0,0,0,0,0};

  uint2 vm = src[0];
#pragma unroll 1
  for (int t = 0; t < TT; ++t) {
    const uint2 v = vm;
    if (t + 1 < TT) vm = src[(size_t)(t + 1) * BB];     // prefetch next t

    // ---- l2 (64 -> 32): two k-slices, scale 2^39; 2-acc chaining ----
    uint32_t om2;
    {
      const uint32_t bl0 = (v.x >> sh) & 0xffffu;
      const uint32_t bl1 = (v.y >> sh) & 0xffffu;
      i32x4 a0, a1;
#pragma unroll
      for (int r = 0; r < 4; ++r) {
        a0[r] = (int)((((bl0 >> (4 * r)) & 15u) * 0x00204081u) & 0x01010101u);
        a1[r] = (int)((((bl1 >> (4 * r)) & 15u) * 0x00204081u) & 0x01010101u);
      }
      i32x16 Acc, Cw;
      Acc = MFI(a0, BL[lane],       zz16);
      Acc = MFI(a1, BL[64 + lane],  Acc);
      Cw  = MFI(a0, BL[128 + lane], zz16);
      Cw  = MFI(a1, BL[192 + lane], Cw);
      Acc += Cw << 8;
      Cw  = MFI(a0, BL[256 + lane], zz16);
      Cw  = MFI(a1, BL[320 + lane], Cw);
      Acc += Cw << 16;
#pragma unroll
      for (int i = 0; i < 16; ++i) {
        const double sub = (m2[i] > 1.0) ? 1.0 : 0.0;
        double md = fma(0.9, m2[i], -sub);
        m2[i] = fma((double)Acc[i], 0x1p-39, md);
      }
      Acc = MFI(a0, BL[384 + lane], zz16);
      Acc = MFI(a1, BL[448 + lane], Acc);
      Cw  = MFI(a0, BL[512 + lane], zz16);
      Cw  = MFI(a1, BL[576 + lane], Cw);
      Acc += Cw << 8;

      unsigned long long sel = 0ull;
#pragma unroll
      for (int i = 0; i < 16; ++i) {
        const double md = fma((double)Acc[i], 0x1p-15, m2[i]);
        m2[i] = md;
        const unsigned long long b = __ballot(md > 1.0);
        sel = (i == 0) ? b : ((rsel == i) ? b : sel);
      }
      om2 = hi_half ? (uint32_t)(sel >> 32) : (uint32_t)sel;
    }

    // ---- l3 (32 -> 32), l4 (32 -> 16 padded), l5 (16 -> 6 padded) ----
    uint32_t om3, om4, om5;
    LSTEP(m3, 640,  om2, om3);
    LSTEP(m4, 960,  om3, om4);
    LSTEP(m5, 1280, om4, om5);

    if (lane < 32) {
      float* op = out + ((size_t)t * BB + ebase + el) * 6;
      ((float2*)op)[0] = make_float2((om5 & 1u)  ? 1.0f : 0.0f,
                                     (om5 & 2u)  ? 1.0f : 0.0f);
      ((float2*)op)[1] = make_float2((om5 & 4u)  ? 1.0f : 0.0f,
                                     (om5 & 8u)  ? 1.0f : 0.0f);
      ((float2*)op)[2] = make_float2((om5 & 16u) ? 1.0f : 0.0f,
                                     (om5 & 32u) ? 1.0f : 0.0f);
    }
  }
}

// ---------------- fallback: monolithic kernel (ws too small; f64 layout) ----------------

__global__ __launch_bounds__(256, 1) void snn_f64(const float* __restrict__ x,
                                                  const double* __restrict__ Wd,
                                                  float* __restrict__ out) {
  const int e = blockIdx.x * blockDim.x + threadIdx.x;

  double m1[64], m2[32], m3[32], m4[16], m5[6];
#pragma unroll
  for (int o = 0; o < 64; ++o) m1[o] = 0.0;
#pragma unroll
  for (int o = 0; o < 32; ++o) m2[o] = 0.0;
#pragma unroll
  for (int o = 0; o < 32; ++o) m3[o] = 0.0;
#pragma unroll
  for (int o = 0; o < 16; ++o) m4[o] = 0.0;
#pragma unroll
  for (int o = 0; o < 6; ++o) m5[o] = 0.0;

#pragma unroll 1
  for (int t = 0; t < TT; ++t) {
    const float* xp = x + ((size_t)t * BB + e) * 10;
    float xv[10];
#pragma unroll
    for (int i = 0; i < 5; ++i) {
      float2 f = ((const float2*)xp)[i];
      xv[2 * i] = f.x; xv[2 * i + 1] = f.y;
    }
#pragma unroll
    for (int o = 0; o < 64; ++o) {
      double sub = (m1[o] > 1.0) ? 1.0 : 0.0;
      m1[o] = 0.9 * m1[o] - sub;
    }
#pragma unroll
    for (int p = 0; p < 2; ++p) {
#pragma unroll
      for (int k = 0; k < 10; ++k) {
        double s = (double)xv[k];
        const double* col = Wd + p * 320 + k * 32;
#pragma unroll
        for (int o = 0; o < 32; ++o) m1[p * 32 + o] = fma(s, col[o], m1[p * 32 + o]);
      }
    }
    unsigned long long msk1 = 0ull;
#pragma unroll
    for (int o = 0; o < 64; ++o) msk1 |= (m1[o] > 1.0) ? (1ull << o) : 0ull;

#pragma unroll
    for (int o = 0; o < 32; ++o) {
      double sub = (m2[o] > 1.0) ? 1.0 : 0.0;
      m2[o] = 0.9 * m2[o] - sub;
    }
    {
      unsigned long long b = msk1;
      const double* col = Wd + OFF_W2T;
      for (int k = 0; k < 64; ++k) {
        double s = (double)(unsigned int)(b & 1ull);
        b >>= 1;
#pragma unroll
        for (int o = 0; o < 32; ++o) m2[o] = fma(s, col[o], m2[o]);
        col += 32;
      }
    }
    unsigned int msk2 = 0u;
#pragma unroll
    for (int o = 0; o < 32; ++o) msk2 |= (m2[o] > 1.0) ? (1u << o) : 0u;

#pragma unroll
    for (int o = 0; o < 32; ++o) {
      double sub = (m3[o] > 1.0) ? 1.0 : 0.0;
      m3[o] = 0.9 * m3[o] - sub;
    }
#pragma unroll
    for (int p = 0; p < 2; ++p) {
      unsigned int b = msk2;
      const double* col = Wd + OFF_W3P + p * 512;
      for (int k = 0; k < 32; ++k) {
        double s = (double)(b & 1u);
        b >>= 1;
#pragma unroll
        for (int o = 0; o < 16; ++o) m3[p * 16 + o] = fma(s, col[o], m3[p * 16 + o]);
        col += 16;
      }
    }
    unsigned int msk3 = 0u;
#pragma unroll
    for (int o = 0; o < 32; ++o) msk3 |= (m3[o] > 1.0) ? (1u << o) : 0u;

#pragma unroll
    for (int o = 0; o < 16; ++o) {
      double sub = (m4[o] > 1.0) ? 1.0 : 0.0;
      m4[o] = 0.9 * m4[o] - sub;
    }
    {
      unsigned int b = msk3;
      const double* col = Wd + OFF_W4T;
      for (int k = 0; k < 32; ++k) {
        double s = (double)(b & 1u);
        b >>= 1;
#pragma unroll
        for (int o = 0; o < 16; ++o) m4[o] = fma(s, col[o], m4[o]);
        col += 16;
      }
    }
    unsigned int msk4 = 0u;
#pragma unroll
    for (int o = 0; o < 16; ++o) msk4 |= (m4[o] > 1.0) ? (1u << o) : 0u;

#pragma unroll
    for (int o = 0; o < 6; ++o) {
      double sub = (m5[o] > 1.0) ? 1.0 : 0.0;
      m5[o] = 0.9 * m5[o] - sub;
    }
    {
      unsigned int b = msk4;
      const double* col = Wd + OFF_W5T;
      for (int k = 0; k < 16; ++k) {
        double s = (double)(b & 1u);
        b >>= 1;
#pragma unroll
        for (int o = 0; o < 6; ++o) m5[o] = fma(s, col[o], m5[o]);
        col += 6;
      }
    }

    float ov[6];
#pragma unroll
    for (int o = 0; o < 6; ++o) ov[o] = (m5[o] > 1.0) ? 1.0f : 0.0f;
    float* op = out + ((size_t)t * BB + e) * 6;
    ((float2*)op)[0] = make_float2(ov[0], ov[1]);
    ((float2*)op)[1] = make_float2(ov[2], ov[3]);
    ((float2*)op)[2] = make_float2(ov[4], ov[5]);
  }
}

extern "C" void kernel_launch(void* const* d_in, const int* in_sizes, int n_in,
                              void* d_out, int out_size, void* d_ws, size_t ws_size,
                              hipStream_t stream) {
  const float* x  = (const float*)d_in[0];
  const float* W1 = (const float*)d_in[1];
  const float* W2 = (const float*)d_in[2];
  const float* W3 = (const float*)d_in[3];
  const float* W4 = (const float*)d_in[4];
  const float* W5 = (const float*)d_in[5];
  float* out = (float*)d_out;
  double* Wd = (double*)d_ws;

  const int mode = (ws_size >= WS_NEEDED) ? 1 : 0;
  prep_weights<<<50, 256, 0, stream>>>(W1, W2, W3, W4, W5, Wd, mode);

  if (mode) {
    char* base = (char*)d_ws;
    uint32_t* P1 = (uint32_t*)(base + WS_MASK_BASE);   // u32[TT][BB][2]
    const uint32_t* B1 = (const uint32_t*)(base + B1_OFFSET);
    snn_l1_mfma<<<2048, 256, 0, stream>>>(x, B1, P1);
    snn_l2345<<<2048, 256, 0, stream>>>(Wd, (const uint32_t*)P1, out);
  } else {
    snn_f64<<<BB / 256, 256, 0, stream>>>(x, Wd, out);
  }
}

// Round 9
// 862.819 us; speedup vs baseline: 1.2510x; 1.2195x over previous
//
#include <hip/hip_runtime.h>
#include <cstdint>
#include <cstddef>

#define TT 20
#define BB 262144

// f64 packed weight layout (element offsets, in doubles):
//   W1H [2][10][32] @ 0     (mode0 fallback; mfma path does not read it)
//   W2T/W3P/W4T/W5T @ 640.. (mode0/fallback only)   total 4320 doubles
//
// mode1 (MFMA path) reuses the dead f64 spans for i8 digit fragments (u32):
//   B2 @ dword 1280: 2560  (l2: 32x32x32, W2 scale 2^39)   [R3/R4-proven]
//   B3 @ dword 3840: 1280  (l3: 32x32x32, W3 scale 2^38)   [R3/R4-proven]
//   B4 @ dword 5120: 1280  (l4: 16x16x64, W4 scale 2^38)   [R5-proven]
//   B5 @ dword 6400: 1280  (l5: 16x16x64, W5 scale 2^38)   [R5-proven]
//   B1 @ tail of P2 span (l1 pair frags) — written by prep, read by l1,
//   clobbered by l2's P2 writes AFTER l1 is done (stream order; R6-proven).
//
// R9: de-fused back to the R6 4-kernel config (best proven 843 us; R7/R8
// fusion was VALU-throughput-bound at ~140 us/tile-layer regardless of
// occupancy — fusion saved only ~13 us HBM + 2 launches but cost registers).
// New: cached-spike sub-reuse (numerically identical): sub at t+1 = spike
// predicate already computed by the ballot at t; cache as f64 sv[] (l2/l3/
// l45) or bit-packed u32 (l1) and drop 16 f64 cmps+selects per tile per t.
#define OFF_W2T 640
#define OFF_W3P 2688
#define OFF_W4T 3712
#define OFF_W5T 4224
#define W_TOTAL 4320
#define B2_DW   1280
#define B3_DW   3840
#define B4_DW   5120
#define B5_DW   6400

// workspace layout (bytes) — same 62,949,376 B budget proven earlier.
//   Wd @ 0 (pad to 34816)
//   P1 @ 34816:    u32[TT][BB][2]  (l1 spikes, [e][part] interleaved)
//   P2 @ 41977856: u32[TT][BB]     (l2 spikes)
//   P3 aliases P1: u32[TT][BB]     (l3 spikes; l1 data dead after l2)
#define WS_MASK_BASE 34816
#define P1_BYTES (2 * (size_t)TT * BB * 4)
#define P2_OFFSET (WS_MASK_BASE + P1_BYTES)
#define P2_BYTES ((size_t)TT * BB * 4)
#define WS_NEEDED (P2_OFFSET + P2_BYTES)
#define B1_BYTES (22 * 256 * 4)                 // 22528
#define B1_OFFSET (WS_NEEDED - B1_BYTES)        // tail of P2 (dead until l2)

typedef __attribute__((ext_vector_type(4))) int i32x4;
typedef __attribute__((ext_vector_type(16))) int i32x16;

// l1 MFMA schedule: {iA, jA, iB, jB} (x-level, w-level per lane-half; iB<0 =>
// half B zero). Rounds: m0-1 -> c3 accL, m2-4 -> c4 accH (scale 2^-49);
// m5-6 -> c5, m7-8 -> c6 (2^-33); m9 -> c7, m10 -> c8 (2^-17).
__constant__ int SCHED[11][4] = {
  {0,3,1,2},{2,1,3,0},{0,4,1,3},{2,2,3,1},{4,0,-1,0},
  {1,4,2,3},{3,2,4,1},{2,4,3,3},{4,2,-1,0},{3,4,4,3},{4,4,-1,0}};

// digit d of the exact signed base-256 decomposition of llrint(w*scale).
__device__ inline uint32_t digit_of(double w, double scale, int d) {
  long long n = llrint(w * scale);
  int dig = 0;
  for (int i = 0; i <= d; ++i) {
    dig = (int)(signed char)((int)(n & 0xffll));
    n = (n - (long long)dig) >> 8;
  }
  return (uint32_t)(dig & 0xff);
}

__global__ void prep_weights(const float* __restrict__ W1, const float* __restrict__ W2,
                             const float* __restrict__ W3, const float* __restrict__ W4,
                             const float* __restrict__ W5, double* __restrict__ Wd, int mode) {
  int stride = blockDim.x * gridDim.x;
  int total = mode ? (7040 + 5632) : W_TOTAL;
  for (int idx = blockIdx.x * blockDim.x + threadIdx.x; idx < total; idx += stride) {
    if (mode) {
      if (idx < 640) {                       // W1H f64 (legacy slot, unused in mode1)
        int j = idx; int p = j / 320, k = (j % 320) / 32, o = j % 32;
        Wd[j] = (double)W1[(p * 32 + o) * 10 + k];
      } else if (idx < 3200) {               // B2 (32x32), scale 2^39
        int j = idx - 640;
        int r = j & 3, lane = (j >> 2) & 63, s = (j >> 8) & 1, d = j >> 9;
        int col = lane & 31, kb = s * 32 + (lane >> 5) * 16 + r * 4;
        uint32_t u = 0;
        for (int jj = 0; jj < 4; ++jj) {
          double w = (double)W2[col * 64 + kb + jj];
          u |= digit_of(w, 0x1p39, d) << (8 * jj);
        }
        ((uint32_t*)Wd)[B2_DW + j] = u;
      } else if (idx < 4480) {               // B3 (32x32), scale 2^38
        int j = idx - 3200;
        int r = j & 3, lane = (j >> 2) & 63, d = j >> 8;
        int col = lane & 31, kb = (lane >> 5) * 16 + r * 4;
        uint32_t u = 0;
        for (int jj = 0; jj < 4; ++jj) {
          double w = (double)W3[col * 32 + kb + jj];
          u |= digit_of(w, 0x1p38, d) << (8 * jj);
        }
        ((uint32_t*)Wd)[B3_DW + j] = u;
      } else if (idx < 5760) {               // B4 (16x16x64), scale 2^38
        int j = idx - 4480;
        int r = j & 3, lane = (j >> 2) & 63, d = j >> 8;
        int col = lane & 15, kb = (lane >> 4) * 16 + r * 4;
        uint32_t u = 0;
        for (int jj = 0; jj < 4; ++jj) {
          int k = kb + jj;
          double w = (k < 32) ? (double)W4[col * 32 + k] : 0.0;
          u |= digit_of(w, 0x1p38, d) << (8 * jj);
        }
        ((uint32_t*)Wd)[B4_DW + j] = u;
      } else if (idx < 7040) {               // B5 (16x16x64), scale 2^38
        int j = idx - 5760;
        int r = j & 3, lane = (j >> 2) & 63, d = j >> 8;
        int col = lane & 15, kb = (lane >> 4) * 16 + r * 4;
        uint32_t u = 0;
        for (int jj = 0; jj < 4; ++jj) {
          int k = kb + jj;
          double w = (k < 16 && col < 6) ? (double)W5[col * 16 + k] : 0.0;
          u |= digit_of(w, 0x1p38, d) << (8 * jj);
        }
        ((uint32_t*)Wd)[B5_DW + j] = u;
      } else {                               // B1 (l1 32x32x32 pair frags), W1 scale 2^38
        int j = idx - 7040;
        int mg = j >> 8, rem = j & 255, lane = rem >> 2, r = rem & 3;
        int tile = mg / 11, sidx = mg % 11, half = lane >> 5;
        int jd   = half ? SCHED[sidx][3] : SCHED[sidx][1];
        int vld  = half ? (SCHED[sidx][2] >= 0) : 1;
        int o = (lane & 31) + 32 * tile;
        uint32_t u = 0;
        if (vld) {
          for (int b = 0; b < 4; ++b) {
            int k = r * 4 + b;
            if (k < 10) u |= digit_of((double)W1[o * 10 + k], 0x1p38, jd) << (8 * b);
          }
        }
        ((uint32_t*)((char*)Wd + B1_OFFSET))[mg * 256 + lane * 4 + r] = u;
      }
    } else {
      double v;
      if (idx < OFF_W2T) {
        int j = idx;            int p = j / 320, k = (j % 320) / 32, o = j % 32;
        v = (double)W1[(p * 32 + o) * 10 + k];
      } else if (idx < OFF_W3P) {
        int j = idx - OFF_W2T;  int k = j / 32, o = j % 32;
        v = (double)W2[o * 64 + k];
      } else if (idx < OFF_W4T) {
        int j = idx - OFF_W3P;  int p = j / 512, k = (j % 512) / 16, o = j % 16;
        v = (double)W3[(p * 16 + o) * 32 + k];
      } else if (idx < OFF_W5T) {
        int j = idx - OFF_W4T;  int k = j / 16, o = j % 16; v = (double)W4[o * 32 + k];
      } else {
        int j = idx - OFF_W5T;  int k = j / 6,  o = j % 6;  v = (double)W5[o * 16 + k];
      }
      Wd[idx] = v;
    }
  }
}

#define MFI(A4, B4, C16) __builtin_amdgcn_mfma_i32_32x32x32_i8((A4), (B4), (C16), 0, 0, 0)

// One out-tile of l1: leak (sub from cached spike bits SPK), 11 MFMAs in 3
// c-rounds, f64 reconstruction.
#define L1_TILE(MA, BASE, SPK)                                                \
  {                                                                           \
    _Pragma("unroll") for (int r2 = 0; r2 < 16; ++r2) {                       \
      const double sub = ((SPK >> r2) & 1u) ? 1.0 : 0.0;                      \
      MA[r2] = fma(0.9, MA[r2], -sub);                                        \
    }                                                                         \
    i32x16 aL, aH;                                                            \
    aL = MFI(hi ? wd1 : wd0, BL[(BASE + 0) * 64 + lane], zz16);               \
    aL = MFI(hi ? wd3 : wd2, BL[(BASE + 1) * 64 + lane], aL);                 \
    aH = MFI(hi ? wd1 : wd0, BL[(BASE + 2) * 64 + lane], zz16);               \
    aH = MFI(hi ? wd3 : wd2, BL[(BASE + 3) * 64 + lane], aH);                 \
    aH = MFI(hi ? zz4 : wd4, BL[(BASE + 4) * 64 + lane], aH);                 \
    _Pragma("unroll") for (int r2 = 0; r2 < 16; ++r2) {                       \
      const int cmb = aL[r2] + (aH[r2] << 8);                                 \
      MA[r2] = fma((double)cmb, 0x1p-49, MA[r2]);                             \
    }                                                                         \
    aL = MFI(hi ? wd2 : wd1, BL[(BASE + 5) * 64 + lane], zz16);               \
    aL = MFI(hi ? wd4 : wd3, BL[(BASE + 6) * 64 + lane], aL);                 \
    aH = MFI(hi ? wd3 : wd2, BL[(BASE + 7) * 64 + lane], zz16);               \
    aH = MFI(hi ? zz4 : wd4, BL[(BASE + 8) * 64 + lane], aH);                 \
    _Pragma("unroll") for (int r2 = 0; r2 < 16; ++r2) {                       \
      const int cmb = aL[r2] + (aH[r2] << 8);                                 \
      MA[r2] = fma((double)cmb, 0x1p-33, MA[r2]);                             \
    }                                                                         \
    aL = MFI(hi ? wd4 : wd3, BL[(BASE + 9) * 64 + lane], zz16);               \
    aH = MFI(hi ? zz4 : wd4, BL[(BASE + 10) * 64 + lane], zz16);              \
    _Pragma("unroll") for (int r2 = 0; r2 < 16; ++r2) {                       \
      const int cmb = aL[r2] + (aH[r2] << 8);                                 \
      MA[r2] = fma((double)cmb, 0x1p-17, MA[r2]);                             \
    }                                                                         \
  }

// Layer 1 (10 -> 64) via i8-digit MFMA (R6-proven). One wave = 32 elems.
__global__ __launch_bounds__(256, 2) void snn_l1_mfma(const float* __restrict__ x,
                                                      const uint32_t* __restrict__ B1g,
                                                      uint32_t* __restrict__ P1) {
  __shared__ __align__(16) uint32_t Bsh[5632];
  for (int i = threadIdx.x; i < 5632; i += 256) Bsh[i] = B1g[i];
  __syncthreads();

  const int lane = threadIdx.x & 63;
  const int wave = threadIdx.x >> 6;
  const int ebase = blockIdx.x * 128 + wave * 32;
  const int el = lane & 31;
  const bool hi = lane >= 32;
  const int rsel = (el & 3) | (((el >> 3) & 3) << 2);   // proven C/D inverse
  const int hi_half = (el >> 2) & 1;
  const i32x4* __restrict__ BL = (const i32x4*)Bsh;

  double m0a[16], m1a[16];
#pragma unroll
  for (int i = 0; i < 16; ++i) { m0a[i] = 0.0; m1a[i] = 0.0; }
  uint32_t spk0 = 0u, spk1 = 0u;   // cached per-lane spike bits (bit i = reg i)

  float2 xf[5];
  {
    const float2* xp = (const float2*)(x + (size_t)(ebase + el) * 10);
#pragma unroll
    for (int i = 0; i < 5; ++i) xf[i] = xp[i];
  }
  uint32_t* __restrict__ dst = P1 + (size_t)(ebase + el) * 2 + (hi ? 1 : 0);

#pragma unroll 1
  for (int t = 0; t < TT; ++t) {
    float xv[10];
#pragma unroll
    for (int i = 0; i < 5; ++i) { xv[2 * i] = xf[i].x; xv[2 * i + 1] = xf[i].y; }
    if (t + 1 < TT) {
      const float2* xn = (const float2*)(x + ((size_t)(t + 1) * BB + ebase + el) * 10);
#pragma unroll
      for (int i = 0; i < 5; ++i) xf[i] = xn[i];
    }

    // x digits: X = x*2^35 = nh*2^16 + nl exactly (two rint splits), then 5
    // signed base-256 digits packed bytewise into wd0..wd4.
    i32x4 wd0 = {0,0,0,0}, wd1 = {0,0,0,0}, wd2 = {0,0,0,0},
          wd3 = {0,0,0,0}, wd4 = {0,0,0,0};
#pragma unroll
    for (int k = 0; k < 10; ++k) {
      const double xd = (double)xv[k];
      const double nhf = rint(xd * 0x1p19);
      int nh = (int)nhf;
      const double r = fma(-nhf, 0x1p-19, xd);          // exact residual
      const int nl = (int)rint(r * 0x1p35);             // |nl| <= 2^15
      const int d0 = ((nl + 128) & 255) - 128;
      const int rem = (nl - d0) >> 8;                   // [-128, 128]
      const int carry = (rem + 128) >> 8;               // 1 iff rem == 128
      const int d1 = rem - (carry << 8);
      nh += carry;
      const int d2 = ((nh + 128) & 255) - 128;
      const int n2 = (nh - d2) >> 8;
      const int d3 = ((n2 + 128) & 255) - 128;
      const int d4 = (n2 - d3) >> 8;
      const int q = k >> 2, sh8 = (k & 3) * 8;
      wd0[q] |= (d0 & 255) << sh8;
      wd1[q] |= (d1 & 255) << sh8;
      wd2[q] |= (d2 & 255) << sh8;
      wd3[q] |= (d3 & 255) << sh8;
      wd4[q] |= (d4 & 255) << sh8;
    }
    const i32x4 zz4 = {0, 0, 0, 0};
    const i32x16 zz16 = {0,0,0,0,0,0,0,0,0,0,0,0,0,0,0,0};

    L1_TILE(m0a, 0, spk0);                              // outputs 0..31
    unsigned long long sel0 = 0ull;
    uint32_t ns0 = 0u;
#pragma unroll
    for (int r2 = 0; r2 < 16; ++r2) {
      const bool sp = m0a[r2] > 1.0;
      const unsigned long long b = __ballot(sp);
      ns0 |= sp ? (1u << r2) : 0u;
      sel0 = (r2 == 0) ? b : ((rsel == r2) ? b : sel0);
    }
    spk0 = ns0;

    L1_TILE(m1a, 11, spk1);                             // outputs 32..63
    unsigned long long sel1 = 0ull;
    uint32_t ns1 = 0u;
#pragma unroll
    for (int r2 = 0; r2 < 16; ++r2) {
      const bool sp = m1a[r2] > 1.0;
      const unsigned long long b = __ballot(sp);
      ns1 |= sp ? (1u << r2) : 0u;
      sel1 = (r2 == 0) ? b : ((rsel == r2) ? b : sel1);
    }
    spk1 = ns1;

    const unsigned long long merged = hi ? sel1 : sel0;
    const uint32_t om = hi_half ? (uint32_t)(merged >> 32) : (uint32_t)merged;
    dst[(size_t)t * BB * 2] = om;                       // full-wave coalesced
  }
}

// Layer 2 (64 -> 32) via i8 MFMA (R4-proven machinery + sv cache, 2-acc chain).
__global__ __launch_bounds__(256, 2) void snn_l2_mfma(const double* __restrict__ Wd,
                                                      const uint32_t* __restrict__ P1,
                                                      uint32_t* __restrict__ P2) {
  __shared__ __align__(16) uint32_t Bsh[2560];
  {
    const uint32_t* __restrict__ Bg = (const uint32_t*)Wd + B2_DW;
    for (int i = threadIdx.x; i < 2560; i += 256) Bsh[i] = Bg[i];
  }
  __syncthreads();

  const int lane = threadIdx.x & 63;
  const int wave = threadIdx.x >> 6;
  const int ebase = blockIdx.x * 128 + wave * 32;
  const int sh = (lane >> 5) * 16;
  const uint2* __restrict__ src = (const uint2*)P1 + (ebase + (lane & 31));
  uint32_t* __restrict__ dst = P2 + ebase;
  const i32x4* __restrict__ BL = (const i32x4*)Bsh;

  const int el = lane & 31;
  const int rsel = (el & 3) | (((el >> 3) & 3) << 2);
  const int hi_half = (el >> 2) & 1;

  double m[16], sv[16];
#pragma unroll
  for (int i = 0; i < 16; ++i) { m[i] = 0.0; sv[i] = 0.0; }

  const i32x16 zz16 = {0,0,0,0,0,0,0,0,0,0,0,0,0,0,0,0};

  uint2 vm = src[0];
#pragma unroll 1
  for (int t = 0; t < TT; ++t) {
    const uint2 v = vm;
    if (t + 1 < TT) vm = src[(size_t)(t + 1) * BB];

    const uint32_t bl0 = (v.x >> sh) & 0xffffu;
    const uint32_t bl1 = (v.y >> sh) & 0xffffu;
    i32x4 a0, a1;
#pragma unroll
    for (int r = 0; r < 4; ++r) {
      a0[r] = (int)((((bl0 >> (4 * r)) & 15u) * 0x00204081u) & 0x01010101u);
      a1[r] = (int)((((bl1 >> (4 * r)) & 15u) * 0x00204081u) & 0x01010101u);
    }
    i32x16 Acc, Cw;
    Acc = MFI(a0, BL[lane],       zz16);
    Acc = MFI(a1, BL[64 + lane],  Acc);
    Cw  = MFI(a0, BL[128 + lane], zz16);
    Cw  = MFI(a1, BL[192 + lane], Cw);
    Acc += Cw << 8;
    Cw  = MFI(a0, BL[256 + lane], zz16);
    Cw  = MFI(a1, BL[320 + lane], Cw);
    Acc += Cw << 16;
#pragma unroll
    for (int i = 0; i < 16; ++i) {
      double md = fma(0.9, m[i], -sv[i]);               // sub from cached spike
      m[i] = fma((double)Acc[i], 0x1p-39, md);
    }
    Acc = MFI(a0, BL[384 + lane], zz16);
    Acc = MFI(a1, BL[448 + lane], Acc);
    Cw  = MFI(a0, BL[512 + lane], zz16);
    Cw  = MFI(a1, BL[576 + lane], Cw);
    Acc += Cw << 8;

    unsigned long long sel = 0ull;
#pragma unroll
    for (int i = 0; i < 16; ++i) {
      const double md = fma((double)Acc[i], 0x1p-15, m[i]);
      m[i] = md;
      const bool sp = md > 1.0;
      sv[i] = sp ? 1.0 : 0.0;                           // cache for next t
      const unsigned long long b = __ballot(sp);
      sel = (i == 0) ? b : ((rsel == i) ? b : sel);
    }
    const uint32_t om = hi_half ? (uint32_t)(sel >> 32) : (uint32_t)sel;
    if (lane < 32) dst[(size_t)t * BB + lane] = om;
  }
}

// Layer 3 (32 -> 32): same machinery, single k-slice, scale 2^38.
__global__ __launch_bounds__(256, 2) void snn_l3_mfma(const double* __restrict__ Wd,
                                                      const uint32_t* __restrict__ P2,
                                                      uint32_t* __restrict__ P3) {
  __shared__ __align__(16) uint32_t Bsh[1280];
  {
    const uint32_t* __restrict__ Bg = (const uint32_t*)Wd + B3_DW;
    for (int i = threadIdx.x; i < 1280; i += 256) Bsh[i] = Bg[i];
  }
  __syncthreads();

  const int lane = threadIdx.x & 63;
  const int wave = threadIdx.x >> 6;
  const int ebase = blockIdx.x * 128 + wave * 32;
  const int sh = (lane >> 5) * 16;
  const uint32_t* __restrict__ src = P2 + (ebase + (lane & 31));
  uint32_t* __restrict__ dst = P3 + ebase;
  const i32x4* __restrict__ BL = (const i32x4*)Bsh;

  const int el = lane & 31;
  const int rsel = (el & 3) | (((el >> 3) & 3) << 2);
  const int hi_half = (el >> 2) & 1;

  double m[16], sv[16];
#pragma unroll
  for (int i = 0; i < 16; ++i) { m[i] = 0.0; sv[i] = 0.0; }

  const i32x16 zz16 = {0,0,0,0,0,0,0,0,0,0,0,0,0,0,0,0};

  uint32_t vm = src[0];
#pragma unroll 1
  for (int t = 0; t < TT; ++t) {
    const uint32_t v = vm;
    if (t + 1 < TT) vm = src[(size_t)(t + 1) * BB];

    const uint32_t bl0 = (v >> sh) & 0xffffu;
    i32x4 a0;
#pragma unroll
    for (int r = 0; r < 4; ++r)
      a0[r] = (int)((((bl0 >> (4 * r)) & 15u) * 0x00204081u) & 0x01010101u);

    i32x16 Acc, Cw;
    Acc = MFI(a0, BL[lane],       zz16);
    Cw  = MFI(a0, BL[64 + lane],  zz16);
    Acc += Cw << 8;
    Cw  = MFI(a0, BL[128 + lane], zz16);
    Acc += Cw << 16;
#pragma unroll
    for (int i = 0; i < 16; ++i) {
      double md = fma(0.9, m[i], -sv[i]);
      m[i] = fma((double)Acc[i], 0x1p-38, md);
    }
    Acc = MFI(a0, BL[192 + lane], zz16);
    Cw  = MFI(a0, BL[256 + lane], zz16);
    Acc += Cw << 8;

    unsigned long long sel = 0ull;
#pragma unroll
    for (int i = 0; i < 16; ++i) {
      const double md = fma((double)Acc[i], 0x1p-14, m[i]);
      m[i] = md;
      const bool sp = md > 1.0;
      sv[i] = sp ? 1.0 : 0.0;
      const unsigned long long b = __ballot(sp);
      sel = (i == 0) ? b : ((rsel == i) ? b : sel);
    }
    const uint32_t om = hi_half ? (uint32_t)(sel >> 32) : (uint32_t)sel;
    if (lane < 32) dst[(size_t)t * BB + lane] = om;
  }
}

// Layers 4+5 fused via 16x16x64 i8 MFMA (R5-proven + sv cache).
__global__ __launch_bounds__(256, 2) void snn_l45_mfma(const double* __restrict__ Wd,
                                                       const uint32_t* __restrict__ P3,
                                                       float* __restrict__ out) {
  __shared__ __align__(16) uint32_t B4sh[1280];
  __shared__ __align__(16) uint32_t B5sh[1280];
  {
    const uint32_t* __restrict__ Bg = (const uint32_t*)Wd;
    for (int i = threadIdx.x; i < 1280; i += 256) {
      B4sh[i] = Bg[B4_DW + i];
      B5sh[i] = Bg[B5_DW + i];
    }
  }
  __syncthreads();

  const int lane = threadIdx.x & 63;
  const int wave = threadIdx.x >> 6;
  const int ebase = blockIdx.x * 64 + wave * 16;
  const int el = lane & 15;
  const int kg = lane >> 4;
  const uint32_t* __restrict__ src = P3 + (ebase + el);
  const i32x4* __restrict__ B4L = (const i32x4*)B4sh;
  const i32x4* __restrict__ B5L = (const i32x4*)B5sh;

  const int rsel = el & 3;
  const int bshift = (el >> 2) * 16;

  double m4[4], m5[4], sv4[4], sv5[4];
#pragma unroll
  for (int r = 0; r < 4; ++r) { m4[r] = 0.0; m5[r] = 0.0; sv4[r] = 0.0; sv5[r] = 0.0; }

  uint32_t vm = src[0];
#pragma unroll 1
  for (int t = 0; t < TT; ++t) {
    const uint32_t v = vm;
    if (t + 1 < TT) vm = src[(size_t)(t + 1) * BB];

    const uint32_t bits = (uint32_t)(((unsigned long long)v >> (kg * 16)) & 0xffffull);
    i32x4 a;
#pragma unroll
    for (int r = 0; r < 4; ++r)
      a[r] = (int)((((bits >> (4 * r)) & 15u) * 0x00204081u) & 0x01010101u);

    const i32x4 z4 = {0, 0, 0, 0};
    i32x4 Slo, Shi, Cw;
    Slo = __builtin_amdgcn_mfma_i32_16x16x64_i8(a, B4L[lane],       z4, 0, 0, 0);
    Cw  = __builtin_amdgcn_mfma_i32_16x16x64_i8(a, B4L[64 + lane],  z4, 0, 0, 0);
    Slo += Cw << 8;
    Cw  = __builtin_amdgcn_mfma_i32_16x16x64_i8(a, B4L[128 + lane], z4, 0, 0, 0);
    Slo += Cw << 16;
    Shi = __builtin_amdgcn_mfma_i32_16x16x64_i8(a, B4L[192 + lane], z4, 0, 0, 0);
    Cw  = __builtin_amdgcn_mfma_i32_16x16x64_i8(a, B4L[256 + lane], z4, 0, 0, 0);
    Shi += Cw << 8;

    unsigned long long sel4 = 0ull;
#pragma unroll
    for (int r = 0; r < 4; ++r) {
      double md = fma(0.9, m4[r], -sv4[r]);
      md = fma((double)Slo[r], 0x1p-38, md);
      md = fma((double)Shi[r], 0x1p-14, md);
      m4[r] = md;
      const bool sp = md > 1.0;
      sv4[r] = sp ? 1.0 : 0.0;
      const unsigned long long b = __ballot(sp);
      sel4 = (r == 0) ? b : ((rsel == r) ? b : sel4);
    }
    const uint32_t msk4 = (uint32_t)(sel4 >> bshift) & 0xffffu;

    const uint32_t bits5 = (kg == 0) ? msk4 : 0u;
    i32x4 a5;
#pragma unroll
    for (int r = 0; r < 4; ++r)
      a5[r] = (int)((((bits5 >> (4 * r)) & 15u) * 0x00204081u) & 0x01010101u);

    Slo = __builtin_amdgcn_mfma_i32_16x16x64_i8(a5, B5L[lane],       z4, 0, 0, 0);
    Cw  = __builtin_amdgcn_mfma_i32_16x16x64_i8(a5, B5L[64 + lane],  z4, 0, 0, 0);
    Slo += Cw << 8;
    Cw  = __builtin_amdgcn_mfma_i32_16x16x64_i8(a5, B5L[128 + lane], z4, 0, 0, 0);
    Slo += Cw << 16;
    Shi = __builtin_amdgcn_mfma_i32_16x16x64_i8(a5, B5L[192 + lane], z4, 0, 0, 0);
    Cw  = __builtin_amdgcn_mfma_i32_16x16x64_i8(a5, B5L[256 + lane], z4, 0, 0, 0);
    Shi += Cw << 8;

    unsigned long long sel5 = 0ull;
#pragma unroll
    for (int r = 0; r < 4; ++r) {
      double md = fma(0.9, m5[r], -sv5[r]);
      md = fma((double)Slo[r], 0x1p-38, md);
      md = fma((double)Shi[r], 0x1p-14, md);
      m5[r] = md;
      const bool sp = md > 1.0;
      sv5[r] = sp ? 1.0 : 0.0;
      const unsigned long long b = __ballot(sp);
      sel5 = (r == 0) ? b : ((rsel == r) ? b : sel5);
    }
    if (lane < 16) {
      const uint32_t om6 = (uint32_t)(sel5 >> bshift) & 0x3fu;
      float* op = out + ((size_t)t * BB + ebase + el) * 6;
      ((float2*)op)[0] = make_float2((om6 & 1u)  ? 1.0f : 0.0f,
                                     (om6 & 2u)  ? 1.0f : 0.0f);
      ((float2*)op)[1] = make_float2((om6 & 4u)  ? 1.0f : 0.0f,
                                     (om6 & 8u)  ? 1.0f : 0.0f);
      ((float2*)op)[2] = make_float2((om6 & 16u) ? 1.0f : 0.0f,
                                     (om6 & 32u) ? 1.0f : 0.0f);
    }
  }
}

// ---------------- fallback: monolithic kernel (ws too small; f64 layout) ----------------

__global__ __launch_bounds__(256, 1) void snn_f64(const float* __restrict__ x,
                                                  const double* __restrict__ Wd,
                                                  float* __restrict__ out) {
  const int e = blockIdx.x * blockDim.x + threadIdx.x;

  double m1[64], m2[32], m3[32], m4[16], m5[6];
#pragma unroll
  for (int o = 0; o < 64; ++o) m1[o] = 0.0;
#pragma unroll
  for (int o = 0; o < 32; ++o) m2[o] = 0.0;
#pragma unroll
  for (int o = 0; o < 32; ++o) m3[o] = 0.0;
#pragma unroll
  for (int o = 0; o < 16; ++o) m4[o] = 0.0;
#pragma unroll
  for (int o = 0; o < 6; ++o) m5[o] = 0.0;

#pragma unroll 1
  for (int t = 0; t < TT; ++t) {
    const float* xp = x + ((size_t)t * BB + e) * 10;
    float xv[10];
#pragma unroll
    for (int i = 0; i < 5; ++i) {
      float2 f = ((const float2*)xp)[i];
      xv[2 * i] = f.x; xv[2 * i + 1] = f.y;
    }
#pragma unroll
    for (int o = 0; o < 64; ++o) {
      double sub = (m1[o] > 1.0) ? 1.0 : 0.0;
      m1[o] = 0.9 * m1[o] - sub;
    }
#pragma unroll
    for (int p = 0; p < 2; ++p) {
#pragma unroll
      for (int k = 0; k < 10; ++k) {
        double s = (double)xv[k];
        const double* col = Wd + p * 320 + k * 32;
#pragma unroll
        for (int o = 0; o < 32; ++o) m1[p * 32 + o] = fma(s, col[o], m1[p * 32 + o]);
      }
    }
    unsigned long long msk1 = 0ull;
#pragma unroll
    for (int o = 0; o < 64; ++o) msk1 |= (m1[o] > 1.0) ? (1ull << o) : 0ull;

#pragma unroll
    for (int o = 0; o < 32; ++o) {
      double sub = (m2[o] > 1.0) ? 1.0 : 0.0;
      m2[o] = 0.9 * m2[o] - sub;
    }
    {
      unsigned long long b = msk1;
      const double* col = Wd + OFF_W2T;
      for (int k = 0; k < 64; ++k) {
        double s = (double)(unsigned int)(b & 1ull);
        b >>= 1;
#pragma unroll
        for (int o = 0; o < 32; ++o) m2[o] = fma(s, col[o], m2[o]);
        col += 32;
      }
    }
    unsigned int msk2 = 0u;
#pragma unroll
    for (int o = 0; o < 32; ++o) msk2 |= (m2[o] > 1.0) ? (1u << o) : 0u;

#pragma unroll
    for (int o = 0; o < 32; ++o) {
      double sub = (m3[o] > 1.0) ? 1.0 : 0.0;
      m3[o] = 0.9 * m3[o] - sub;
    }
#pragma unroll
    for (int p = 0; p < 2; ++p) {
      unsigned int b = msk2;
      const double* col = Wd + OFF_W3P + p * 512;
      for (int k = 0; k < 32; ++k) {
        double s = (double)(b & 1u);
        b >>= 1;
#pragma unroll
        for (int o = 0; o < 16; ++o) m3[p * 16 + o] = fma(s, col[o], m3[p * 16 + o]);
        col += 16;
      }
    }
    unsigned int msk3 = 0u;
#pragma unroll
    for (int o = 0; o < 32; ++o) msk3 |= (m3[o] > 1.0) ? (1u << o) : 0u;

#pragma unroll
    for (int o = 0; o < 16; ++o) {
      double sub = (m4[o] > 1.0) ? 1.0 : 0.0;
      m4[o] = 0.9 * m4[o] - sub;
    }
    {
      unsigned int b = msk3;
      const double* col = Wd + OFF_W4T;
      for (int k = 0; k < 32; ++k) {
        double s = (double)(b & 1u);
        b >>= 1;
#pragma unroll
        for (int o = 0; o < 16; ++o) m4[o] = fma(s, col[o], m4[o]);
        col += 16;
      }
    }
    unsigned int msk4 = 0u;
#pragma unroll
    for (int o = 0; o < 16; ++o) msk4 |= (m4[o] > 1.0) ? (1u << o) : 0u;

#pragma unroll
    for (int o = 0; o < 6; ++o) {
      double sub = (m5[o] > 1.0) ? 1.0 : 0.0;
      m5[o] = 0.9 * m5[o] - sub;
    }
    {
      unsigned int b = msk4;
      const double* col = Wd + OFF_W5T;
      for (int k = 0; k < 16; ++k) {
        double s = (double)(b & 1u);
        b >>= 1;
#pragma unroll
        for (int o = 0; o < 6; ++o) m5[o] = fma(s, col[o], m5[o]);
        col += 6;
      }
    }

    float ov[6];
#pragma unroll
    for (int o = 0; o < 6; ++o) ov[o] = (m5[o] > 1.0) ? 1.0f : 0.0f;
    float* op = out + ((size_t)t * BB + e) * 6;
    ((float2*)op)[0] = make_float2(ov[0], ov[1]);
    ((float2*)op)[1] = make_float2(ov[2], ov[3]);
    ((float2*)op)[2] = make_float2(ov[4], ov[5]);
  }
}

extern "C" void kernel_launch(void* const* d_in, const int* in_sizes, int n_in,
                              void* d_out, int out_size, void* d_ws, size_t ws_size,
                              hipStream_t stream) {
  const float* x  = (const float*)d_in[0];
  const float* W1 = (const float*)d_in[1];
  const float* W2 = (const float*)d_in[2];
  const float* W3 = (const float*)d_in[3];
  const float* W4 = (const float*)d_in[4];
  const float* W5 = (const float*)d_in[5];
  float* out = (float*)d_out;
  double* Wd = (double*)d_ws;

  const int mode = (ws_size >= WS_NEEDED) ? 1 : 0;
  prep_weights<<<50, 256, 0, stream>>>(W1, W2, W3, W4, W5, Wd, mode);

  if (mode) {
    char* base = (char*)d_ws;
    uint32_t* P1 = (uint32_t*)(base + WS_MASK_BASE);   // u32[TT][BB][2]
    uint32_t* P2 = (uint32_t*)(base + P2_OFFSET);      // u32[TT][BB]
    uint32_t* P3 = (uint32_t*)(base + WS_MASK_BASE);   // u32[TT][BB], aliases P1
    const uint32_t* B1 = (const uint32_t*)(base + B1_OFFSET);  // tail of P2; dead once l2 runs
    snn_l1_mfma<<<2048, 256, 0, stream>>>(x, B1, P1);
    snn_l2_mfma<<<2048, 256, 0, stream>>>(Wd, P1, P2);
    snn_l3_mfma<<<2048, 256, 0, stream>>>(Wd, P2, P3);
    snn_l45_mfma<<<BB / 64, 256, 0, stream>>>(Wd, (const uint32_t*)P3, out);
  } else {
    snn_f64<<<BB / 256, 256, 0, stream>>>(x, Wd, out);
  }
}

// Round 10
// 847.154 us; speedup vs baseline: 1.2741x; 1.0185x over previous
//
#include <hip/hip_runtime.h>
#include <cstdint>
#include <cstddef>

#define TT 20
#define BB 262144

// f64 packed weight layout (element offsets, in doubles):
//   W1H [2][10][32] @ 0     (mode0 fallback; mfma path does not read it)
//   W2T/W3P/W4T/W5T @ 640.. (mode0/fallback only)   total 4320 doubles
//
// mode1 (MFMA path) reuses the dead f64 spans for i8 digit fragments (u32):
//   B2 @ dword 1280: 2560  (l2: 32x32x32, W2 scale 2^39)   [R3/R4-proven]
//   B3 @ dword 3840: 1280  (l3: 32x32x32, W3 scale 2^38)   [R3/R4-proven]
//   B4 @ dword 5120: 1280  (l4: 16x16x64, W4 scale 2^38)   [R5-proven]
//   B5 @ dword 6400: 1280  (l5: 16x16x64, W5 scale 2^38)   [R5-proven]
//   B1 @ tail of P2 span (l1 pair frags) — written by prep, read by l1,
//   clobbered by l2's P2 writes AFTER l1 is done (stream order; R6-proven).
//
// R10: surgical recombination of the R9 split decision.
//   - l1: R6 body verbatim (338 us measured; R9's bit-packed spk cache cost
//     +53 us via unpack chain + spill growth 66->94 MB). One change only:
//     launch_bounds (256,1) — R6's VGPR=128 sat exactly at the (256,2) cap
//     with ~25 MB spill-writes; headroom should kill the spill while actual
//     usage (~200 unified) still grants 2 waves/SIMD.
//   - l2/l3/l45: R9 sv-cache versions verbatim (back-half 505->471 us,
//     absmax=0 proven).
#define OFF_W2T 640
#define OFF_W3P 2688
#define OFF_W4T 3712
#define OFF_W5T 4224
#define W_TOTAL 4320
#define B2_DW   1280
#define B3_DW   3840
#define B4_DW   5120
#define B5_DW   6400

// workspace layout (bytes) — same 62,949,376 B budget proven earlier.
//   Wd @ 0 (pad to 34816)
//   P1 @ 34816:    u32[TT][BB][2]  (l1 spikes, [e][part] interleaved)
//   P2 @ 41977856: u32[TT][BB]     (l2 spikes)
//   P3 aliases P1: u32[TT][BB]     (l3 spikes; l1 data dead after l2)
#define WS_MASK_BASE 34816
#define P1_BYTES (2 * (size_t)TT * BB * 4)
#define P2_OFFSET (WS_MASK_BASE + P1_BYTES)
#define P2_BYTES ((size_t)TT * BB * 4)
#define WS_NEEDED (P2_OFFSET + P2_BYTES)
#define B1_BYTES (22 * 256 * 4)                 // 22528
#define B1_OFFSET (WS_NEEDED - B1_BYTES)        // tail of P2 (dead until l2)

typedef __attribute__((ext_vector_type(4))) int i32x4;
typedef __attribute__((ext_vector_type(16))) int i32x16;

// l1 MFMA schedule: {iA, jA, iB, jB} (x-level, w-level per lane-half; iB<0 =>
// half B zero). Rounds: m0-1 -> c3 accL, m2-4 -> c4 accH (scale 2^-49);
// m5-6 -> c5, m7-8 -> c6 (2^-33); m9 -> c7, m10 -> c8 (2^-17).
__constant__ int SCHED[11][4] = {
  {0,3,1,2},{2,1,3,0},{0,4,1,3},{2,2,3,1},{4,0,-1,0},
  {1,4,2,3},{3,2,4,1},{2,4,3,3},{4,2,-1,0},{3,4,4,3},{4,4,-1,0}};

// digit d of the exact signed base-256 decomposition of llrint(w*scale).
__device__ inline uint32_t digit_of(double w, double scale, int d) {
  long long n = llrint(w * scale);
  int dig = 0;
  for (int i = 0; i <= d; ++i) {
    dig = (int)(signed char)((int)(n & 0xffll));
    n = (n - (long long)dig) >> 8;
  }
  return (uint32_t)(dig & 0xff);
}

__global__ void prep_weights(const float* __restrict__ W1, const float* __restrict__ W2,
                             const float* __restrict__ W3, const float* __restrict__ W4,
                             const float* __restrict__ W5, double* __restrict__ Wd, int mode) {
  int stride = blockDim.x * gridDim.x;
  int total = mode ? (7040 + 5632) : W_TOTAL;
  for (int idx = blockIdx.x * blockDim.x + threadIdx.x; idx < total; idx += stride) {
    if (mode) {
      if (idx < 640) {                       // W1H f64 (legacy slot, unused in mode1)
        int j = idx; int p = j / 320, k = (j % 320) / 32, o = j % 32;
        Wd[j] = (double)W1[(p * 32 + o) * 10 + k];
      } else if (idx < 3200) {               // B2 (32x32), scale 2^39
        int j = idx - 640;
        int r = j & 3, lane = (j >> 2) & 63, s = (j >> 8) & 1, d = j >> 9;
        int col = lane & 31, kb = s * 32 + (lane >> 5) * 16 + r * 4;
        uint32_t u = 0;
        for (int jj = 0; jj < 4; ++jj) {
          double w = (double)W2[col * 64 + kb + jj];
          u |= digit_of(w, 0x1p39, d) << (8 * jj);
        }
        ((uint32_t*)Wd)[B2_DW + j] = u;
      } else if (idx < 4480) {               // B3 (32x32), scale 2^38
        int j = idx - 3200;
        int r = j & 3, lane = (j >> 2) & 63, d = j >> 8;
        int col = lane & 31, kb = (lane >> 5) * 16 + r * 4;
        uint32_t u = 0;
        for (int jj = 0; jj < 4; ++jj) {
          double w = (double)W3[col * 32 + kb + jj];
          u |= digit_of(w, 0x1p38, d) << (8 * jj);
        }
        ((uint32_t*)Wd)[B3_DW + j] = u;
      } else if (idx < 5760) {               // B4 (16x16x64), scale 2^38
        int j = idx - 4480;
        int r = j & 3, lane = (j >> 2) & 63, d = j >> 8;
        int col = lane & 15, kb = (lane >> 4) * 16 + r * 4;
        uint32_t u = 0;
        for (int jj = 0; jj < 4; ++jj) {
          int k = kb + jj;
          double w = (k < 32) ? (double)W4[col * 32 + k] : 0.0;
          u |= digit_of(w, 0x1p38, d) << (8 * jj);
        }
        ((uint32_t*)Wd)[B4_DW + j] = u;
      } else if (idx < 7040) {               // B5 (16x16x64), scale 2^38
        int j = idx - 5760;
        int r = j & 3, lane = (j >> 2) & 63, d = j >> 8;
        int col = lane & 15, kb = (lane >> 4) * 16 + r * 4;
        uint32_t u = 0;
        for (int jj = 0; jj < 4; ++jj) {
          int k = kb + jj;
          double w = (k < 16 && col < 6) ? (double)W5[col * 16 + k] : 0.0;
          u |= digit_of(w, 0x1p38, d) << (8 * jj);
        }
        ((uint32_t*)Wd)[B5_DW + j] = u;
      } else {                               // B1 (l1 32x32x32 pair frags), W1 scale 2^38
        int j = idx - 7040;
        int mg = j >> 8, rem = j & 255, lane = rem >> 2, r = rem & 3;
        int tile = mg / 11, sidx = mg % 11, half = lane >> 5;
        int jd   = half ? SCHED[sidx][3] : SCHED[sidx][1];
        int vld  = half ? (SCHED[sidx][2] >= 0) : 1;
        int o = (lane & 31) + 32 * tile;
        uint32_t u = 0;
        if (vld) {
          for (int b = 0; b < 4; ++b) {
            int k = r * 4 + b;
            if (k < 10) u |= digit_of((double)W1[o * 10 + k], 0x1p38, jd) << (8 * b);
          }
        }
        ((uint32_t*)((char*)Wd + B1_OFFSET))[mg * 256 + lane * 4 + r] = u;
      }
    } else {
      double v;
      if (idx < OFF_W2T) {
        int j = idx;            int p = j / 320, k = (j % 320) / 32, o = j % 32;
        v = (double)W1[(p * 32 + o) * 10 + k];
      } else if (idx < OFF_W3P) {
        int j = idx - OFF_W2T;  int k = j / 32, o = j % 32;
        v = (double)W2[o * 64 + k];
      } else if (idx < OFF_W4T) {
        int j = idx - OFF_W3P;  int p = j / 512, k = (j % 512) / 16, o = j % 16;
        v = (double)W3[(p * 16 + o) * 32 + k];
      } else if (idx < OFF_W5T) {
        int j = idx - OFF_W4T;  int k = j / 16, o = j % 16; v = (double)W4[o * 32 + k];
      } else {
        int j = idx - OFF_W5T;  int k = j / 6,  o = j % 6;  v = (double)W5[o * 16 + k];
      }
      Wd[idx] = v;
    }
  }
}

#define MFI(A4, B4, C16) __builtin_amdgcn_mfma_i32_32x32x32_i8((A4), (B4), (C16), 0, 0, 0)

// One out-tile of l1: leak, 11 MFMAs in 3 c-rounds, f64 reconstruction.
// (R6 form: f64 compare leak — measured faster than bit-unpack cache.)
#define L1_TILE(MA, BASE)                                                     \
  {                                                                           \
    _Pragma("unroll") for (int r2 = 0; r2 < 16; ++r2) {                       \
      const double sub = (MA[r2] > 1.0) ? 1.0 : 0.0;                          \
      MA[r2] = fma(0.9, MA[r2], -sub);                                        \
    }                                                                         \
    i32x16 aL, aH;                                                            \
    aL = MFI(hi ? wd1 : wd0, BL[(BASE + 0) * 64 + lane], zz16);               \
    aL = MFI(hi ? wd3 : wd2, BL[(BASE + 1) * 64 + lane], aL);                 \
    aH = MFI(hi ? wd1 : wd0, BL[(BASE + 2) * 64 + lane], zz16);               \
    aH = MFI(hi ? wd3 : wd2, BL[(BASE + 3) * 64 + lane], aH);                 \
    aH = MFI(hi ? zz4 : wd4, BL[(BASE + 4) * 64 + lane], aH);                 \
    _Pragma("unroll") for (int r2 = 0; r2 < 16; ++r2) {                       \
      const int cmb = aL[r2] + (aH[r2] << 8);                                 \
      MA[r2] = fma((double)cmb, 0x1p-49, MA[r2]);                             \
    }                                                                         \
    aL = MFI(hi ? wd2 : wd1, BL[(BASE + 5) * 64 + lane], zz16);               \
    aL = MFI(hi ? wd4 : wd3, BL[(BASE + 6) * 64 + lane], aL);                 \
    aH = MFI(hi ? wd3 : wd2, BL[(BASE + 7) * 64 + lane], zz16);               \
    aH = MFI(hi ? zz4 : wd4, BL[(BASE + 8) * 64 + lane], aH);                 \
    _Pragma("unroll") for (int r2 = 0; r2 < 16; ++r2) {                       \
      const int cmb = aL[r2] + (aH[r2] << 8);                                 \
      MA[r2] = fma((double)cmb, 0x1p-33, MA[r2]);                             \
    }                                                                         \
    aL = MFI(hi ? wd4 : wd3, BL[(BASE + 9) * 64 + lane], zz16);               \
    aH = MFI(hi ? zz4 : wd4, BL[(BASE + 10) * 64 + lane], zz16);              \
    _Pragma("unroll") for (int r2 = 0; r2 < 16; ++r2) {                       \
      const int cmb = aL[r2] + (aH[r2] << 8);                                 \
      MA[r2] = fma((double)cmb, 0x1p-17, MA[r2]);                             \
    }                                                                         \
  }

// Layer 1 (10 -> 64) via i8-digit MFMA (R6 body; launch_bounds relaxed to
// (256,1) to lift the 128-VGPR cap that caused ~25 MB of spill writes).
__global__ __launch_bounds__(256, 1) void snn_l1_mfma(const float* __restrict__ x,
                                                      const uint32_t* __restrict__ B1g,
                                                      uint32_t* __restrict__ P1) {
  __shared__ __align__(16) uint32_t Bsh[5632];
  for (int i = threadIdx.x; i < 5632; i += 256) Bsh[i] = B1g[i];
  __syncthreads();

  const int lane = threadIdx.x & 63;
  const int wave = threadIdx.x >> 6;
  const int ebase = blockIdx.x * 128 + wave * 32;
  const int el = lane & 31;
  const bool hi = lane >= 32;
  const int rsel = (el & 3) | (((el >> 3) & 3) << 2);   // proven C/D inverse
  const int hi_half = (el >> 2) & 1;
  const i32x4* __restrict__ BL = (const i32x4*)Bsh;

  double m0a[16], m1a[16];
#pragma unroll
  for (int i = 0; i < 16; ++i) { m0a[i] = 0.0; m1a[i] = 0.0; }

  float2 xf[5];
  {
    const float2* xp = (const float2*)(x + (size_t)(ebase + el) * 10);
#pragma unroll
    for (int i = 0; i < 5; ++i) xf[i] = xp[i];
  }
  uint32_t* __restrict__ dst = P1 + (size_t)(ebase + el) * 2 + (hi ? 1 : 0);

#pragma unroll 1
  for (int t = 0; t < TT; ++t) {
    float xv[10];
#pragma unroll
    for (int i = 0; i < 5; ++i) { xv[2 * i] = xf[i].x; xv[2 * i + 1] = xf[i].y; }
    if (t + 1 < TT) {
      const float2* xn = (const float2*)(x + ((size_t)(t + 1) * BB + ebase + el) * 10);
#pragma unroll
      for (int i = 0; i < 5; ++i) xf[i] = xn[i];
    }

    // x digits: X = x*2^35 = nh*2^16 + nl exactly (two rint splits), then 5
    // signed base-256 digits packed bytewise into wd0..wd4.
    i32x4 wd0 = {0,0,0,0}, wd1 = {0,0,0,0}, wd2 = {0,0,0,0},
          wd3 = {0,0,0,0}, wd4 = {0,0,0,0};
#pragma unroll
    for (int k = 0; k < 10; ++k) {
      const double xd = (double)xv[k];
      const double nhf = rint(xd * 0x1p19);
      int nh = (int)nhf;
      const double r = fma(-nhf, 0x1p-19, xd);          // exact residual
      const int nl = (int)rint(r * 0x1p35);             // |nl| <= 2^15
      const int d0 = ((nl + 128) & 255) - 128;
      const int rem = (nl - d0) >> 8;                   // [-128, 128]
      const int carry = (rem + 128) >> 8;               // 1 iff rem == 128
      const int d1 = rem - (carry << 8);
      nh += carry;
      const int d2 = ((nh + 128) & 255) - 128;
      const int n2 = (nh - d2) >> 8;
      const int d3 = ((n2 + 128) & 255) - 128;
      const int d4 = (n2 - d3) >> 8;
      const int q = k >> 2, sh8 = (k & 3) * 8;
      wd0[q] |= (d0 & 255) << sh8;
      wd1[q] |= (d1 & 255) << sh8;
      wd2[q] |= (d2 & 255) << sh8;
      wd3[q] |= (d3 & 255) << sh8;
      wd4[q] |= (d4 & 255) << sh8;
    }
    const i32x4 zz4 = {0, 0, 0, 0};
    const i32x16 zz16 = {0,0,0,0,0,0,0,0,0,0,0,0,0,0,0,0};

    L1_TILE(m0a, 0);                                    // outputs 0..31
    unsigned long long sel0 = 0ull;
#pragma unroll
    for (int r2 = 0; r2 < 16; ++r2) {
      const unsigned long long b = __ballot(m0a[r2] > 1.0);
      sel0 = (r2 == 0) ? b : ((rsel == r2) ? b : sel0);
    }

    L1_TILE(m1a, 11);                                   // outputs 32..63
    unsigned long long sel1 = 0ull;
#pragma unroll
    for (int r2 = 0; r2 < 16; ++r2) {
      const unsigned long long b = __ballot(m1a[r2] > 1.0);
      sel1 = (r2 == 0) ? b : ((rsel == r2) ? b : sel1);
    }

    const unsigned long long merged = hi ? sel1 : sel0;
    const uint32_t om = hi_half ? (uint32_t)(merged >> 32) : (uint32_t)merged;
    dst[(size_t)t * BB * 2] = om;                       // full-wave coalesced
  }
}

// Layer 2 (64 -> 32) via i8 MFMA (R9-proven: sv cache + 2-acc chain).
__global__ __launch_bounds__(256, 2) void snn_l2_mfma(const double* __restrict__ Wd,
                                                      const uint32_t* __restrict__ P1,
                                                      uint32_t* __restrict__ P2) {
  __shared__ __align__(16) uint32_t Bsh[2560];
  {
    const uint32_t* __restrict__ Bg = (const uint32_t*)Wd + B2_DW;
    for (int i = threadIdx.x; i < 2560; i += 256) Bsh[i] = Bg[i];
  }
  __syncthreads();

  const int lane = threadIdx.x & 63;
  const int wave = threadIdx.x >> 6;
  const int ebase = blockIdx.x * 128 + wave * 32;
  const int sh = (lane >> 5) * 16;
  const uint2* __restrict__ src = (const uint2*)P1 + (ebase + (lane & 31));
  uint32_t* __restrict__ dst = P2 + ebase;
  const i32x4* __restrict__ BL = (const i32x4*)Bsh;

  const int el = lane & 31;
  const int rsel = (el & 3) | (((el >> 3) & 3) << 2);
  const int hi_half = (el >> 2) & 1;

  double m[16], sv[16];
#pragma unroll
  for (int i = 0; i < 16; ++i) { m[i] = 0.0; sv[i] = 0.0; }

  const i32x16 zz16 = {0,0,0,0,0,0,0,0,0,0,0,0,0,0,0,0};

  uint2 vm = src[0];
#pragma unroll 1
  for (int t = 0; t < TT; ++t) {
    const uint2 v = vm;
    if (t + 1 < TT) vm = src[(size_t)(t + 1) * BB];

    const uint32_t bl0 = (v.x >> sh) & 0xffffu;
    const uint32_t bl1 = (v.y >> sh) & 0xffffu;
    i32x4 a0, a1;
#pragma unroll
    for (int r = 0; r < 4; ++r) {
      a0[r] = (int)((((bl0 >> (4 * r)) & 15u) * 0x00204081u) & 0x01010101u);
      a1[r] = (int)((((bl1 >> (4 * r)) & 15u) * 0x00204081u) & 0x01010101u);
    }
    i32x16 Acc, Cw;
    Acc = MFI(a0, BL[lane],       zz16);
    Acc = MFI(a1, BL[64 + lane],  Acc);
    Cw  = MFI(a0, BL[128 + lane], zz16);
    Cw  = MFI(a1, BL[192 + lane], Cw);
    Acc += Cw << 8;
    Cw  = MFI(a0, BL[256 + lane], zz16);
    Cw  = MFI(a1, BL[320 + lane], Cw);
    Acc += Cw << 16;
#pragma unroll
    for (int i = 0; i < 16; ++i) {
      double md = fma(0.9, m[i], -sv[i]);               // sub from cached spike
      m[i] = fma((double)Acc[i], 0x1p-39, md);
    }
    Acc = MFI(a0, BL[384 + lane], zz16);
    Acc = MFI(a1, BL[448 + lane], Acc);
    Cw  = MFI(a0, BL[512 + lane], zz16);
    Cw  = MFI(a1, BL[576 + lane], Cw);
    Acc += Cw << 8;

    unsigned long long sel = 0ull;
#pragma unroll
    for (int i = 0; i < 16; ++i) {
      const double md = fma((double)Acc[i], 0x1p-15, m[i]);
      m[i] = md;
      const bool sp = md > 1.0;
      sv[i] = sp ? 1.0 : 0.0;                           // cache for next t
      const unsigned long long b = __ballot(sp);
      sel = (i == 0) ? b : ((rsel == i) ? b : sel);
    }
    const uint32_t om = hi_half ? (uint32_t)(sel >> 32) : (uint32_t)sel;
    if (lane < 32) dst[(size_t)t * BB + lane] = om;
  }
}

// Layer 3 (32 -> 32): same machinery, single k-slice, scale 2^38.
__global__ __launch_bounds__(256, 2) void snn_l3_mfma(const double* __restrict__ Wd,
                                                      const uint32_t* __restrict__ P2,
                                                      uint32_t* __restrict__ P3) {
  __shared__ __align__(16) uint32_t Bsh[1280];
  {
    const uint32_t* __restrict__ Bg = (const uint32_t*)Wd + B3_DW;
    for (int i = threadIdx.x; i < 1280; i += 256) Bsh[i] = Bg[i];
  }
  __syncthreads();

  const int lane = threadIdx.x & 63;
  const int wave = threadIdx.x >> 6;
  const int ebase = blockIdx.x * 128 + wave * 32;
  const int sh = (lane >> 5) * 16;
  const uint32_t* __restrict__ src = P2 + (ebase + (lane & 31));
  uint32_t* __restrict__ dst = P3 + ebase;
  const i32x4* __restrict__ BL = (const i32x4*)Bsh;

  const int el = lane & 31;
  const int rsel = (el & 3) | (((el >> 3) & 3) << 2);
  const int hi_half = (el >> 2) & 1;

  double m[16], sv[16];
#pragma unroll
  for (int i = 0; i < 16; ++i) { m[i] = 0.0; sv[i] = 0.0; }

  const i32x16 zz16 = {0,0,0,0,0,0,0,0,0,0,0,0,0,0,0,0};

  uint32_t vm = src[0];
#pragma unroll 1
  for (int t = 0; t < TT; ++t) {
    const uint32_t v = vm;
    if (t + 1 < TT) vm = src[(size_t)(t + 1) * BB];

    const uint32_t bl0 = (v >> sh) & 0xffffu;
    i32x4 a0;
#pragma unroll
    for (int r = 0; r < 4; ++r)
      a0[r] = (int)((((bl0 >> (4 * r)) & 15u) * 0x00204081u) & 0x01010101u);

    i32x16 Acc, Cw;
    Acc = MFI(a0, BL[lane],       zz16);
    Cw  = MFI(a0, BL[64 + lane],  zz16);
    Acc += Cw << 8;
    Cw  = MFI(a0, BL[128 + lane], zz16);
    Acc += Cw << 16;
#pragma unroll
    for (int i = 0; i < 16; ++i) {
      double md = fma(0.9, m[i], -sv[i]);
      m[i] = fma((double)Acc[i], 0x1p-38, md);
    }
    Acc = MFI(a0, BL[192 + lane], zz16);
    Cw  = MFI(a0, BL[256 + lane], zz16);
    Acc += Cw << 8;

    unsigned long long sel = 0ull;
#pragma unroll
    for (int i = 0; i < 16; ++i) {
      const double md = fma((double)Acc[i], 0x1p-14, m[i]);
      m[i] = md;
      const bool sp = md > 1.0;
      sv[i] = sp ? 1.0 : 0.0;
      const unsigned long long b = __ballot(sp);
      sel = (i == 0) ? b : ((rsel == i) ? b : sel);
    }
    const uint32_t om = hi_half ? (uint32_t)(sel >> 32) : (uint32_t)sel;
    if (lane < 32) dst[(size_t)t * BB + lane] = om;
  }
}

// Layers 4+5 fused via 16x16x64 i8 MFMA (R9-proven: sv cache).
__global__ __launch_bounds__(256, 2) void snn_l45_mfma(const double* __restrict__ Wd,
                                                       const uint32_t* __restrict__ P3,
                                                       float* __restrict__ out) {
  __shared__ __align__(16) uint32_t B4sh[1280];
  __shared__ __align__(16) uint32_t B5sh[1280];
  {
    const uint32_t* __restrict__ Bg = (const uint32_t*)Wd;
    for (int i = threadIdx.x; i < 1280; i += 256) {
      B4sh[i] = Bg[B4_DW + i];
      B5sh[i] = Bg[B5_DW + i];
    }
  }
  __syncthreads();

  const int lane = threadIdx.x & 63;
  const int wave = threadIdx.x >> 6;
  const int ebase = blockIdx.x * 64 + wave * 16;
  const int el = lane & 15;
  const int kg = lane >> 4;
  const uint32_t* __restrict__ src = P3 + (ebase + el);
  const i32x4* __restrict__ B4L = (const i32x4*)B4sh;
  const i32x4* __restrict__ B5L = (const i32x4*)B5sh;

  const int rsel = el & 3;
  const int bshift = (el >> 2) * 16;

  double m4[4], m5[4], sv4[4], sv5[4];
#pragma unroll
  for (int r = 0; r < 4; ++r) { m4[r] = 0.0; m5[r] = 0.0; sv4[r] = 0.0; sv5[r] = 0.0; }

  uint32_t vm = src[0];
#pragma unroll 1
  for (int t = 0; t < TT; ++t) {
    const uint32_t v = vm;
    if (t + 1 < TT) vm = src[(size_t)(t + 1) * BB];

    const uint32_t bits = (uint32_t)(((unsigned long long)v >> (kg * 16)) & 0xffffull);
    i32x4 a;
#pragma unroll
    for (int r = 0; r < 4; ++r)
      a[r] = (int)((((bits >> (4 * r)) & 15u) * 0x00204081u) & 0x01010101u);

    const i32x4 z4 = {0, 0, 0, 0};
    i32x4 Slo, Shi, Cw;
    Slo = __builtin_amdgcn_mfma_i32_16x16x64_i8(a, B4L[lane],       z4, 0, 0, 0);
    Cw  = __builtin_amdgcn_mfma_i32_16x16x64_i8(a, B4L[64 + lane],  z4, 0, 0, 0);
    Slo += Cw << 8;
    Cw  = __builtin_amdgcn_mfma_i32_16x16x64_i8(a, B4L[128 + lane], z4, 0, 0, 0);
    Slo += Cw << 16;
    Shi = __builtin_amdgcn_mfma_i32_16x16x64_i8(a, B4L[192 + lane], z4, 0, 0, 0);
    Cw  = __builtin_amdgcn_mfma_i32_16x16x64_i8(a, B4L[256 + lane], z4, 0, 0, 0);
    Shi += Cw << 8;

    unsigned long long sel4 = 0ull;
#pragma unroll
    for (int r = 0; r < 4; ++r) {
      double md = fma(0.9, m4[r], -sv4[r]);
      md = fma((double)Slo[r], 0x1p-38, md);
      md = fma((double)Shi[r], 0x1p-14, md);
      m4[r] = md;
      const bool sp = md > 1.0;
      sv4[r] = sp ? 1.0 : 0.0;
      const unsigned long long b = __ballot(sp);
      sel4 = (r == 0) ? b : ((rsel == r) ? b : sel4);
    }
    const uint32_t msk4 = (uint32_t)(sel4 >> bshift) & 0xffffu;

    const uint32_t bits5 = (kg == 0) ? msk4 : 0u;
    i32x4 a5;
#pragma unroll
    for (int r = 0; r < 4; ++r)
      a5[r] = (int)((((bits5 >> (4 * r)) & 15u) * 0x00204081u) & 0x01010101u);

    Slo = __builtin_amdgcn_mfma_i32_16x16x64_i8(a5, B5L[lane],       z4, 0, 0, 0);
    Cw  = __builtin_amdgcn_mfma_i32_16x16x64_i8(a5, B5L[64 + lane],  z4, 0, 0, 0);
    Slo += Cw << 8;
    Cw  = __builtin_amdgcn_mfma_i32_16x16x64_i8(a5, B5L[128 + lane], z4, 0, 0, 0);
    Slo += Cw << 16;
    Shi = __builtin_amdgcn_mfma_i32_16x16x64_i8(a5, B5L[192 + lane], z4, 0, 0, 0);
    Cw  = __builtin_amdgcn_mfma_i32_16x16x64_i8(a5, B5L[256 + lane], z4, 0, 0, 0);
    Shi += Cw << 8;

    unsigned long long sel5 = 0ull;
#pragma unroll
    for (int r = 0; r < 4; ++r) {
      double md = fma(0.9, m5[r], -sv5[r]);
      md = fma((double)Slo[r], 0x1p-38, md);
      md = fma((double)Shi[r], 0x1p-14, md);
      m5[r] = md;
      const bool sp = md > 1.0;
      sv5[r] = sp ? 1.0 : 0.0;
      const unsigned long long b = __ballot(sp);
      sel5 = (r == 0) ? b : ((rsel == r) ? b : sel5);
    }
    if (lane < 16) {
      const uint32_t om6 = (uint32_t)(sel5 >> bshift) & 0x3fu;
      float* op = out + ((size_t)t * BB + ebase + el) * 6;
      ((float2*)op)[0] = make_float2((om6 & 1u)  ? 1.0f : 0.0f,
                                     (om6 & 2u)  ? 1.0f : 0.0f);
      ((float2*)op)[1] = make_float2((om6 & 4u)  ? 1.0f : 0.0f,
                                     (om6 & 8u)  ? 1.0f : 0.0f);
      ((float2*)op)[2] = make_float2((om6 & 16u) ? 1.0f : 0.0f,
                                     (om6 & 32u) ? 1.0f : 0.0f);
    }
  }
}

// ---------------- fallback: monolithic kernel (ws too small; f64 layout) ----------------

__global__ __launch_bounds__(256, 1) void snn_f64(const float* __restrict__ x,
                                                  const double* __restrict__ Wd,
                                                  float* __restrict__ out) {
  const int e = blockIdx.x * blockDim.x + threadIdx.x;

  double m1[64], m2[32], m3[32], m4[16], m5[6];
#pragma unroll
  for (int o = 0; o < 64; ++o) m1[o] = 0.0;
#pragma unroll
  for (int o = 0; o < 32; ++o) m2[o] = 0.0;
#pragma unroll
  for (int o = 0; o < 32; ++o) m3[o] = 0.0;
#pragma unroll
  for (int o = 0; o < 16; ++o) m4[o] = 0.0;
#pragma unroll
  for (int o = 0; o < 6; ++o) m5[o] = 0.0;

#pragma unroll 1
  for (int t = 0; t < TT; ++t) {
    const float* xp = x + ((size_t)t * BB + e) * 10;
    float xv[10];
#pragma unroll
    for (int i = 0; i < 5; ++i) {
      float2 f = ((const float2*)xp)[i];
      xv[2 * i] = f.x; xv[2 * i + 1] = f.y;
    }
#pragma unroll
    for (int o = 0; o < 64; ++o) {
      double sub = (m1[o] > 1.0) ? 1.0 : 0.0;
      m1[o] = 0.9 * m1[o] - sub;
    }
#pragma unroll
    for (int p = 0; p < 2; ++p) {
#pragma unroll
      for (int k = 0; k < 10; ++k) {
        double s = (double)xv[k];
        const double* col = Wd + p * 320 + k * 32;
#pragma unroll
        for (int o = 0; o < 32; ++o) m1[p * 32 + o] = fma(s, col[o], m1[p * 32 + o]);
      }
    }
    unsigned long long msk1 = 0ull;
#pragma unroll
    for (int o = 0; o < 64; ++o) msk1 |= (m1[o] > 1.0) ? (1ull << o) : 0ull;

#pragma unroll
    for (int o = 0; o < 32; ++o) {
      double sub = (m2[o] > 1.0) ? 1.0 : 0.0;
      m2[o] = 0.9 * m2[o] - sub;
    }
    {
      unsigned long long b = msk1;
      const double* col = Wd + OFF_W2T;
      for (int k = 0; k < 64; ++k) {
        double s = (double)(unsigned int)(b & 1ull);
        b >>= 1;
#pragma unroll
        for (int o = 0; o < 32; ++o) m2[o] = fma(s, col[o], m2[o]);
        col += 32;
      }
    }
    unsigned int msk2 = 0u;
#pragma unroll
    for (int o = 0; o < 32; ++o) msk2 |= (m2[o] > 1.0) ? (1u << o) : 0u;

#pragma unroll
    for (int o = 0; o < 32; ++o) {
      double sub = (m3[o] > 1.0) ? 1.0 : 0.0;
      m3[o] = 0.9 * m3[o] - sub;
    }
#pragma unroll
    for (int p = 0; p < 2; ++p) {
      unsigned int b = msk2;
      const double* col = Wd + OFF_W3P + p * 512;
      for (int k = 0; k < 32; ++k) {
        double s = (double)(b & 1u);
        b >>= 1;
#pragma unroll
        for (int o = 0; o < 16; ++o) m3[p * 16 + o] = fma(s, col[o], m3[p * 16 + o]);
        col += 16;
      }
    }
    unsigned int msk3 = 0u;
#pragma unroll
    for (int o = 0; o < 32; ++o) msk3 |= (m3[o] > 1.0) ? (1u << o) : 0u;

#pragma unroll
    for (int o = 0; o < 16; ++o) {
      double sub = (m4[o] > 1.0) ? 1.0 : 0.0;
      m4[o] = 0.9 * m4[o] - sub;
    }
    {
      unsigned int b = msk3;
      const double* col = Wd + OFF_W4T;
      for (int k = 0; k < 32; ++k) {
        double s = (double)(b & 1u);
        b >>= 1;
#pragma unroll
        for (int o = 0; o < 16; ++o) m4[o] = fma(s, col[o], m4[o]);
        col += 16;
      }
    }
    unsigned int msk4 = 0u;
#pragma unroll
    for (int o = 0; o < 16; ++o) msk4 |= (m4[o] > 1.0) ? (1u << o) : 0u;

#pragma unroll
    for (int o = 0; o < 6; ++o) {
      double sub = (m5[o] > 1.0) ? 1.0 : 0.0;
      m5[o] = 0.9 * m5[o] - sub;
    }
    {
      unsigned int b = msk4;
      const double* col = Wd + OFF_W5T;
      for (int k = 0; k < 16; ++k) {
        double s = (double)(b & 1u);
        b >>= 1;
#pragma unroll
        for (int o = 0; o < 6; ++o) m5[o] = fma(s, col[o], m5[o]);
        col += 6;
      }
    }

    float ov[6];
#pragma unroll
    for (int o = 0; o < 6; ++o) ov[o] = (m5[o] > 1.0) ? 1.0f : 0.0f;
    float* op = out + ((size_t)t * BB + e) * 6;
    ((float2*)op)[0] = make_float2(ov[0], ov[1]);
    ((float2*)op)[1] = make_float2(ov[2], ov[3]);
    ((float2*)op)[2] = make_float2(ov[4], ov[5]);
  }
}

extern "C" void kernel_launch(void* const* d_in, const int* in_sizes, int n_in,
                              void* d_out, int out_size, void* d_ws, size_t ws_size,
                              hipStream_t stream) {
  const float* x  = (const float*)d_in[0];
  const float* W1 = (const float*)d_in[1];
  const float* W2 = (const float*)d_in[2];
  const float* W3 = (const float*)d_in[3];
  const float* W4 = (const float*)d_in[4];
  const float* W5 = (const float*)d_in[5];
  float* out = (float*)d_out;
  double* Wd = (double*)d_ws;

  const int mode = (ws_size >= WS_NEEDED) ? 1 : 0;
  prep_weights<<<50, 256, 0, stream>>>(W1, W2, W3, W4, W5, Wd, mode);

  if (mode) {
    char* base = (char*)d_ws;
    uint32_t* P1 = (uint32_t*)(base + WS_MASK_BASE);   // u32[TT][BB][2]
    uint32_t* P2 = (uint32_t*)(base + P2_OFFSET);      // u32[TT][BB]
    uint32_t* P3 = (uint32_t*)(base + WS_MASK_BASE);   // u32[TT][BB], aliases P1
    const uint32_t* B1 = (const uint32_t*)(base + B1_OFFSET);  // tail of P2; dead once l2 runs
    snn_l1_mfma<<<2048, 256, 0, stream>>>(x, B1, P1);
    snn_l2_mfma<<<2048, 256, 0, stream>>>(Wd, P1, P2);
    snn_l3_mfma<<<2048, 256, 0, stream>>>(Wd, P2, P3);
    snn_l45_mfma<<<BB / 64, 256, 0, stream>>>(Wd, (const uint32_t*)P3, out);
  } else {
    snn_f64<<<BB / 256, 256, 0, stream>>>(x, Wd, out);
  }
}

// Round 11
// 811.284 us; speedup vs baseline: 1.3304x; 1.0442x over previous
//
#include <hip/hip_runtime.h>
#include <cstdint>
#include <cstddef>

#define TT 20
#define BB 262144

// f64 packed weight layout (element offsets, in doubles):
//   W1H [2][10][32] @ 0     (mode0 fallback; mfma path does not read it)
//   W2T/W3P/W4T/W5T @ 640.. (mode0/fallback only)   total 4320 doubles
//
// mode1 (MFMA path) reuses the dead f64 spans for i8 digit fragments (u32):
//   B2 @ dword 1280: 2560  (l2: 32x32x32, W2 scale 2^39)   [R3/R4-proven]
//   B3 @ dword 3840: 1280  (l3: 32x32x32, W3 scale 2^38)   [R3/R4-proven]
//   B4 @ dword 5120: 1280  (l4: 16x16x64, W4 scale 2^38)   [R5-proven]
//   B5 @ dword 6400: 1280  (l5: 16x16x64, W5 scale 2^38)   [R5-proven]
//   B1 @ tail of P2 span (l1 pair frags) — written by prep, read by l1,
//   clobbered by l2's P2 writes AFTER l1 is done (stream order; R6-proven).
//
// R11: single-variable revert after R10's occupancy lesson.
//   Measured l1 ranking: (256,2)+~25MB spill = 338 us  <  (256,1) no-spill
//   = 385 us (occupancy 21.5%->11.6%: allocator claimed a 512-reg 1-wave
//   budget; no co-resident wave to hide MFMA/LDS/ballot latency)  <
//   (256,2)+spk-cache = 391 us. The 25 MB spill (~8 us HBM) is cheaper than
//   losing the 2nd wave/SIMD. l1 = R6-exact config; back-half = R9 sv-cache
//   (measured 462 us incl. prep).
#define OFF_W2T 640
#define OFF_W3P 2688
#define OFF_W4T 3712
#define OFF_W5T 4224
#define W_TOTAL 4320
#define B2_DW   1280
#define B3_DW   3840
#define B4_DW   5120
#define B5_DW   6400

// workspace layout (bytes) — same 62,949,376 B budget proven earlier.
//   Wd @ 0 (pad to 34816)
//   P1 @ 34816:    u32[TT][BB][2]  (l1 spikes, [e][part] interleaved)
//   P2 @ 41977856: u32[TT][BB]     (l2 spikes)
//   P3 aliases P1: u32[TT][BB]     (l3 spikes; l1 data dead after l2)
#define WS_MASK_BASE 34816
#define P1_BYTES (2 * (size_t)TT * BB * 4)
#define P2_OFFSET (WS_MASK_BASE + P1_BYTES)
#define P2_BYTES ((size_t)TT * BB * 4)
#define WS_NEEDED (P2_OFFSET + P2_BYTES)
#define B1_BYTES (22 * 256 * 4)                 // 22528
#define B1_OFFSET (WS_NEEDED - B1_BYTES)        // tail of P2 (dead until l2)

typedef __attribute__((ext_vector_type(4))) int i32x4;
typedef __attribute__((ext_vector_type(16))) int i32x16;

// l1 MFMA schedule: {iA, jA, iB, jB} (x-level, w-level per lane-half; iB<0 =>
// half B zero). Rounds: m0-1 -> c3 accL, m2-4 -> c4 accH (scale 2^-49);
// m5-6 -> c5, m7-8 -> c6 (2^-33); m9 -> c7, m10 -> c8 (2^-17).
__constant__ int SCHED[11][4] = {
  {0,3,1,2},{2,1,3,0},{0,4,1,3},{2,2,3,1},{4,0,-1,0},
  {1,4,2,3},{3,2,4,1},{2,4,3,3},{4,2,-1,0},{3,4,4,3},{4,4,-1,0}};

// digit d of the exact signed base-256 decomposition of llrint(w*scale).
__device__ inline uint32_t digit_of(double w, double scale, int d) {
  long long n = llrint(w * scale);
  int dig = 0;
  for (int i = 0; i <= d; ++i) {
    dig = (int)(signed char)((int)(n & 0xffll));
    n = (n - (long long)dig) >> 8;
  }
  return (uint32_t)(dig & 0xff);
}

__global__ void prep_weights(const float* __restrict__ W1, const float* __restrict__ W2,
                             const float* __restrict__ W3, const float* __restrict__ W4,
                             const float* __restrict__ W5, double* __restrict__ Wd, int mode) {
  int stride = blockDim.x * gridDim.x;
  int total = mode ? (7040 + 5632) : W_TOTAL;
  for (int idx = blockIdx.x * blockDim.x + threadIdx.x; idx < total; idx += stride) {
    if (mode) {
      if (idx < 640) {                       // W1H f64 (legacy slot, unused in mode1)
        int j = idx; int p = j / 320, k = (j % 320) / 32, o = j % 32;
        Wd[j] = (double)W1[(p * 32 + o) * 10 + k];
      } else if (idx < 3200) {               // B2 (32x32), scale 2^39
        int j = idx - 640;
        int r = j & 3, lane = (j >> 2) & 63, s = (j >> 8) & 1, d = j >> 9;
        int col = lane & 31, kb = s * 32 + (lane >> 5) * 16 + r * 4;
        uint32_t u = 0;
        for (int jj = 0; jj < 4; ++jj) {
          double w = (double)W2[col * 64 + kb + jj];
          u |= digit_of(w, 0x1p39, d) << (8 * jj);
        }
        ((uint32_t*)Wd)[B2_DW + j] = u;
      } else if (idx < 4480) {               // B3 (32x32), scale 2^38
        int j = idx - 3200;
        int r = j & 3, lane = (j >> 2) & 63, d = j >> 8;
        int col = lane & 31, kb = (lane >> 5) * 16 + r * 4;
        uint32_t u = 0;
        for (int jj = 0; jj < 4; ++jj) {
          double w = (double)W3[col * 32 + kb + jj];
          u |= digit_of(w, 0x1p38, d) << (8 * jj);
        }
        ((uint32_t*)Wd)[B3_DW + j] = u;
      } else if (idx < 5760) {               // B4 (16x16x64), scale 2^38
        int j = idx - 4480;
        int r = j & 3, lane = (j >> 2) & 63, d = j >> 8;
        int col = lane & 15, kb = (lane >> 4) * 16 + r * 4;
        uint32_t u = 0;
        for (int jj = 0; jj < 4; ++jj) {
          int k = kb + jj;
          double w = (k < 32) ? (double)W4[col * 32 + k] : 0.0;
          u |= digit_of(w, 0x1p38, d) << (8 * jj);
        }
        ((uint32_t*)Wd)[B4_DW + j] = u;
      } else if (idx < 7040) {               // B5 (16x16x64), scale 2^38
        int j = idx - 5760;
        int r = j & 3, lane = (j >> 2) & 63, d = j >> 8;
        int col = lane & 15, kb = (lane >> 4) * 16 + r * 4;
        uint32_t u = 0;
        for (int jj = 0; jj < 4; ++jj) {
          int k = kb + jj;
          double w = (k < 16 && col < 6) ? (double)W5[col * 16 + k] : 0.0;
          u |= digit_of(w, 0x1p38, d) << (8 * jj);
        }
        ((uint32_t*)Wd)[B5_DW + j] = u;
      } else {                               // B1 (l1 32x32x32 pair frags), W1 scale 2^38
        int j = idx - 7040;
        int mg = j >> 8, rem = j & 255, lane = rem >> 2, r = rem & 3;
        int tile = mg / 11, sidx = mg % 11, half = lane >> 5;
        int jd   = half ? SCHED[sidx][3] : SCHED[sidx][1];
        int vld  = half ? (SCHED[sidx][2] >= 0) : 1;
        int o = (lane & 31) + 32 * tile;
        uint32_t u = 0;
        if (vld) {
          for (int b = 0; b < 4; ++b) {
            int k = r * 4 + b;
            if (k < 10) u |= digit_of((double)W1[o * 10 + k], 0x1p38, jd) << (8 * b);
          }
        }
        ((uint32_t*)((char*)Wd + B1_OFFSET))[mg * 256 + lane * 4 + r] = u;
      }
    } else {
      double v;
      if (idx < OFF_W2T) {
        int j = idx;            int p = j / 320, k = (j % 320) / 32, o = j % 32;
        v = (double)W1[(p * 32 + o) * 10 + k];
      } else if (idx < OFF_W3P) {
        int j = idx - OFF_W2T;  int k = j / 32, o = j % 32;
        v = (double)W2[o * 64 + k];
      } else if (idx < OFF_W4T) {
        int j = idx - OFF_W3P;  int p = j / 512, k = (j % 512) / 16, o = j % 16;
        v = (double)W3[(p * 16 + o) * 32 + k];
      } else if (idx < OFF_W5T) {
        int j = idx - OFF_W4T;  int k = j / 16, o = j % 16; v = (double)W4[o * 32 + k];
      } else {
        int j = idx - OFF_W5T;  int k = j / 6,  o = j % 6;  v = (double)W5[o * 16 + k];
      }
      Wd[idx] = v;
    }
  }
}

#define MFI(A4, B4, C16) __builtin_amdgcn_mfma_i32_32x32x32_i8((A4), (B4), (C16), 0, 0, 0)

// One out-tile of l1: leak, 11 MFMAs in 3 c-rounds, f64 reconstruction.
#define L1_TILE(MA, BASE)                                                     \
  {                                                                           \
    _Pragma("unroll") for (int r2 = 0; r2 < 16; ++r2) {                       \
      const double sub = (MA[r2] > 1.0) ? 1.0 : 0.0;                          \
      MA[r2] = fma(0.9, MA[r2], -sub);                                        \
    }                                                                         \
    i32x16 aL, aH;                                                            \
    aL = MFI(hi ? wd1 : wd0, BL[(BASE + 0) * 64 + lane], zz16);               \
    aL = MFI(hi ? wd3 : wd2, BL[(BASE + 1) * 64 + lane], aL);                 \
    aH = MFI(hi ? wd1 : wd0, BL[(BASE + 2) * 64 + lane], zz16);               \
    aH = MFI(hi ? wd3 : wd2, BL[(BASE + 3) * 64 + lane], aH);                 \
    aH = MFI(hi ? zz4 : wd4, BL[(BASE + 4) * 64 + lane], aH);                 \
    _Pragma("unroll") for (int r2 = 0; r2 < 16; ++r2) {                       \
      const int cmb = aL[r2] + (aH[r2] << 8);                                 \
      MA[r2] = fma((double)cmb, 0x1p-49, MA[r2]);                             \
    }                                                                         \
    aL = MFI(hi ? wd2 : wd1, BL[(BASE + 5) * 64 + lane], zz16);               \
    aL = MFI(hi ? wd4 : wd3, BL[(BASE + 6) * 64 + lane], aL);                 \
    aH = MFI(hi ? wd3 : wd2, BL[(BASE + 7) * 64 + lane], zz16);               \
    aH = MFI(hi ? zz4 : wd4, BL[(BASE + 8) * 64 + lane], aH);                 \
    _Pragma("unroll") for (int r2 = 0; r2 < 16; ++r2) {                       \
      const int cmb = aL[r2] + (aH[r2] << 8);                                 \
      MA[r2] = fma((double)cmb, 0x1p-33, MA[r2]);                             \
    }                                                                         \
    aL = MFI(hi ? wd4 : wd3, BL[(BASE + 9) * 64 + lane], zz16);               \
    aH = MFI(hi ? zz4 : wd4, BL[(BASE + 10) * 64 + lane], zz16);              \
    _Pragma("unroll") for (int r2 = 0; r2 < 16; ++r2) {                       \
      const int cmb = aL[r2] + (aH[r2] << 8);                                 \
      MA[r2] = fma((double)cmb, 0x1p-17, MA[r2]);                             \
    }                                                                         \
  }

// Layer 1 (10 -> 64) via i8-digit MFMA — R6-exact config, measured 338 us.
__global__ __launch_bounds__(256, 2) void snn_l1_mfma(const float* __restrict__ x,
                                                      const uint32_t* __restrict__ B1g,
                                                      uint32_t* __restrict__ P1) {
  __shared__ __align__(16) uint32_t Bsh[5632];
  for (int i = threadIdx.x; i < 5632; i += 256) Bsh[i] = B1g[i];
  __syncthreads();

  const int lane = threadIdx.x & 63;
  const int wave = threadIdx.x >> 6;
  const int ebase = blockIdx.x * 128 + wave * 32;
  const int el = lane & 31;
  const bool hi = lane >= 32;
  const int rsel = (el & 3) | (((el >> 3) & 3) << 2);   // proven C/D inverse
  const int hi_half = (el >> 2) & 1;
  const i32x4* __restrict__ BL = (const i32x4*)Bsh;

  double m0a[16], m1a[16];
#pragma unroll
  for (int i = 0; i < 16; ++i) { m0a[i] = 0.0; m1a[i] = 0.0; }

  float2 xf[5];
  {
    const float2* xp = (const float2*)(x + (size_t)(ebase + el) * 10);
#pragma unroll
    for (int i = 0; i < 5; ++i) xf[i] = xp[i];
  }
  uint32_t* __restrict__ dst = P1 + (size_t)(ebase + el) * 2 + (hi ? 1 : 0);

#pragma unroll 1
  for (int t = 0; t < TT; ++t) {
    float xv[10];
#pragma unroll
    for (int i = 0; i < 5; ++i) { xv[2 * i] = xf[i].x; xv[2 * i + 1] = xf[i].y; }
    if (t + 1 < TT) {
      const float2* xn = (const float2*)(x + ((size_t)(t + 1) * BB + ebase + el) * 10);
#pragma unroll
      for (int i = 0; i < 5; ++i) xf[i] = xn[i];
    }

    // x digits: X = x*2^35 = nh*2^16 + nl exactly (two rint splits), then 5
    // signed base-256 digits packed bytewise into wd0..wd4.
    i32x4 wd0 = {0,0,0,0}, wd1 = {0,0,0,0}, wd2 = {0,0,0,0},
          wd3 = {0,0,0,0}, wd4 = {0,0,0,0};
#pragma unroll
    for (int k = 0; k < 10; ++k) {
      const double xd = (double)xv[k];
      const double nhf = rint(xd * 0x1p19);
      int nh = (int)nhf;
      const double r = fma(-nhf, 0x1p-19, xd);          // exact residual
      const int nl = (int)rint(r * 0x1p35);             // |nl| <= 2^15
      const int d0 = ((nl + 128) & 255) - 128;
      const int rem = (nl - d0) >> 8;                   // [-128, 128]
      const int carry = (rem + 128) >> 8;               // 1 iff rem == 128
      const int d1 = rem - (carry << 8);
      nh += carry;
      const int d2 = ((nh + 128) & 255) - 128;
      const int n2 = (nh - d2) >> 8;
      const int d3 = ((n2 + 128) & 255) - 128;
      const int d4 = (n2 - d3) >> 8;
      const int q = k >> 2, sh8 = (k & 3) * 8;
      wd0[q] |= (d0 & 255) << sh8;
      wd1[q] |= (d1 & 255) << sh8;
      wd2[q] |= (d2 & 255) << sh8;
      wd3[q] |= (d3 & 255) << sh8;
      wd4[q] |= (d4 & 255) << sh8;
    }
    const i32x4 zz4 = {0, 0, 0, 0};
    const i32x16 zz16 = {0,0,0,0,0,0,0,0,0,0,0,0,0,0,0,0};

    L1_TILE(m0a, 0);                                    // outputs 0..31
    unsigned long long sel0 = 0ull;
#pragma unroll
    for (int r2 = 0; r2 < 16; ++r2) {
      const unsigned long long b = __ballot(m0a[r2] > 1.0);
      sel0 = (r2 == 0) ? b : ((rsel == r2) ? b : sel0);
    }

    L1_TILE(m1a, 11);                                   // outputs 32..63
    unsigned long long sel1 = 0ull;
#pragma unroll
    for (int r2 = 0; r2 < 16; ++r2) {
      const unsigned long long b = __ballot(m1a[r2] > 1.0);
      sel1 = (r2 == 0) ? b : ((rsel == r2) ? b : sel1);
    }

    const unsigned long long merged = hi ? sel1 : sel0;
    const uint32_t om = hi_half ? (uint32_t)(merged >> 32) : (uint32_t)merged;
    dst[(size_t)t * BB * 2] = om;                       // full-wave coalesced
  }
}

// Layer 2 (64 -> 32) via i8 MFMA (R9-proven: sv cache + 2-acc chain).
__global__ __launch_bounds__(256, 2) void snn_l2_mfma(const double* __restrict__ Wd,
                                                      const uint32_t* __restrict__ P1,
                                                      uint32_t* __restrict__ P2) {
  __shared__ __align__(16) uint32_t Bsh[2560];
  {
    const uint32_t* __restrict__ Bg = (const uint32_t*)Wd + B2_DW;
    for (int i = threadIdx.x; i < 2560; i += 256) Bsh[i] = Bg[i];
  }
  __syncthreads();

  const int lane = threadIdx.x & 63;
  const int wave = threadIdx.x >> 6;
  const int ebase = blockIdx.x * 128 + wave * 32;
  const int sh = (lane >> 5) * 16;
  const uint2* __restrict__ src = (const uint2*)P1 + (ebase + (lane & 31));
  uint32_t* __restrict__ dst = P2 + ebase;
  const i32x4* __restrict__ BL = (const i32x4*)Bsh;

  const int el = lane & 31;
  const int rsel = (el & 3) | (((el >> 3) & 3) << 2);
  const int hi_half = (el >> 2) & 1;

  double m[16], sv[16];
#pragma unroll
  for (int i = 0; i < 16; ++i) { m[i] = 0.0; sv[i] = 0.0; }

  const i32x16 zz16 = {0,0,0,0,0,0,0,0,0,0,0,0,0,0,0,0};

  uint2 vm = src[0];
#pragma unroll 1
  for (int t = 0; t < TT; ++t) {
    const uint2 v = vm;
    if (t + 1 < TT) vm = src[(size_t)(t + 1) * BB];

    const uint32_t bl0 = (v.x >> sh) & 0xffffu;
    const uint32_t bl1 = (v.y >> sh) & 0xffffu;
    i32x4 a0, a1;
#pragma unroll
    for (int r = 0; r < 4; ++r) {
      a0[r] = (int)((((bl0 >> (4 * r)) & 15u) * 0x00204081u) & 0x01010101u);
      a1[r] = (int)((((bl1 >> (4 * r)) & 15u) * 0x00204081u) & 0x01010101u);
    }
    i32x16 Acc, Cw;
    Acc = MFI(a0, BL[lane],       zz16);
    Acc = MFI(a1, BL[64 + lane],  Acc);
    Cw  = MFI(a0, BL[128 + lane], zz16);
    Cw  = MFI(a1, BL[192 + lane], Cw);
    Acc += Cw << 8;
    Cw  = MFI(a0, BL[256 + lane], zz16);
    Cw  = MFI(a1, BL[320 + lane], Cw);
    Acc += Cw << 16;
#pragma unroll
    for (int i = 0; i < 16; ++i) {
      double md = fma(0.9, m[i], -sv[i]);               // sub from cached spike
      m[i] = fma((double)Acc[i], 0x1p-39, md);
    }
    Acc = MFI(a0, BL[384 + lane], zz16);
    Acc = MFI(a1, BL[448 + lane], Acc);
    Cw  = MFI(a0, BL[512 + lane], zz16);
    Cw  = MFI(a1, BL[576 + lane], Cw);
    Acc += Cw << 8;

    unsigned long long sel = 0ull;
#pragma unroll
    for (int i = 0; i < 16; ++i) {
      const double md = fma((double)Acc[i], 0x1p-15, m[i]);
      m[i] = md;
      const bool sp = md > 1.0;
      sv[i] = sp ? 1.0 : 0.0;                           // cache for next t
      const unsigned long long b = __ballot(sp);
      sel = (i == 0) ? b : ((rsel == i) ? b : sel);
    }
    const uint32_t om = hi_half ? (uint32_t)(sel >> 32) : (uint32_t)sel;
    if (lane < 32) dst[(size_t)t * BB + lane] = om;
  }
}

// Layer 3 (32 -> 32): same machinery, single k-slice, scale 2^38.
__global__ __launch_bounds__(256, 2) void snn_l3_mfma(const double* __restrict__ Wd,
                                                      const uint32_t* __restrict__ P2,
                                                      uint32_t* __restrict__ P3) {
  __shared__ __align__(16) uint32_t Bsh[1280];
  {
    const uint32_t* __restrict__ Bg = (const uint32_t*)Wd + B3_DW;
    for (int i = threadIdx.x; i < 1280; i += 256) Bsh[i] = Bg[i];
  }
  __syncthreads();

  const int lane = threadIdx.x & 63;
  const int wave = threadIdx.x >> 6;
  const int ebase = blockIdx.x * 128 + wave * 32;
  const int sh = (lane >> 5) * 16;
  const uint32_t* __restrict__ src = P2 + (ebase + (lane & 31));
  uint32_t* __restrict__ dst = P3 + ebase;
  const i32x4* __restrict__ BL = (const i32x4*)Bsh;

  const int el = lane & 31;
  const int rsel = (el & 3) | (((el >> 3) & 3) << 2);
  const int hi_half = (el >> 2) & 1;

  double m[16], sv[16];
#pragma unroll
  for (int i = 0; i < 16; ++i) { m[i] = 0.0; sv[i] = 0.0; }

  const i32x16 zz16 = {0,0,0,0,0,0,0,0,0,0,0,0,0,0,0,0};

  uint32_t vm = src[0];
#pragma unroll 1
  for (int t = 0; t < TT; ++t) {
    const uint32_t v = vm;
    if (t + 1 < TT) vm = src[(size_t)(t + 1) * BB];

    const uint32_t bl0 = (v >> sh) & 0xffffu;
    i32x4 a0;
#pragma unroll
    for (int r = 0; r < 4; ++r)
      a0[r] = (int)((((bl0 >> (4 * r)) & 15u) * 0x00204081u) & 0x01010101u);

    i32x16 Acc, Cw;
    Acc = MFI(a0, BL[lane],       zz16);
    Cw  = MFI(a0, BL[64 + lane],  zz16);
    Acc += Cw << 8;
    Cw  = MFI(a0, BL[128 + lane], zz16);
    Acc += Cw << 16;
#pragma unroll
    for (int i = 0; i < 16; ++i) {
      double md = fma(0.9, m[i], -sv[i]);
      m[i] = fma((double)Acc[i], 0x1p-38, md);
    }
    Acc = MFI(a0, BL[192 + lane], zz16);
    Cw  = MFI(a0, BL[256 + lane], zz16);
    Acc += Cw << 8;

    unsigned long long sel = 0ull;
#pragma unroll
    for (int i = 0; i < 16; ++i) {
      const double md = fma((double)Acc[i], 0x1p-14, m[i]);
      m[i] = md;
      const bool sp = md > 1.0;
      sv[i] = sp ? 1.0 : 0.0;
      const unsigned long long b = __ballot(sp);
      sel = (i == 0) ? b : ((rsel == i) ? b : sel);
    }
    const uint32_t om = hi_half ? (uint32_t)(sel >> 32) : (uint32_t)sel;
    if (lane < 32) dst[(size_t)t * BB + lane] = om;
  }
}

// Layers 4+5 fused via 16x16x64 i8 MFMA (R9-proven: sv cache).
__global__ __launch_bounds__(256, 2) void snn_l45_mfma(const double* __restrict__ Wd,
                                                       const uint32_t* __restrict__ P3,
                                                       float* __restrict__ out) {
  __shared__ __align__(16) uint32_t B4sh[1280];
  __shared__ __align__(16) uint32_t B5sh[1280];
  {
    const uint32_t* __restrict__ Bg = (const uint32_t*)Wd;
    for (int i = threadIdx.x; i < 1280; i += 256) {
      B4sh[i] = Bg[B4_DW + i];
      B5sh[i] = Bg[B5_DW + i];
    }
  }
  __syncthreads();

  const int lane = threadIdx.x & 63;
  const int wave = threadIdx.x >> 6;
  const int ebase = blockIdx.x * 64 + wave * 16;
  const int el = lane & 15;
  const int kg = lane >> 4;
  const uint32_t* __restrict__ src = P3 + (ebase + el);
  const i32x4* __restrict__ B4L = (const i32x4*)B4sh;
  const i32x4* __restrict__ B5L = (const i32x4*)B5sh;

  const int rsel = el & 3;
  const int bshift = (el >> 2) * 16;

  double m4[4], m5[4], sv4[4], sv5[4];
#pragma unroll
  for (int r = 0; r < 4; ++r) { m4[r] = 0.0; m5[r] = 0.0; sv4[r] = 0.0; sv5[r] = 0.0; }

  uint32_t vm = src[0];
#pragma unroll 1
  for (int t = 0; t < TT; ++t) {
    const uint32_t v = vm;
    if (t + 1 < TT) vm = src[(size_t)(t + 1) * BB];

    const uint32_t bits = (uint32_t)(((unsigned long long)v >> (kg * 16)) & 0xffffull);
    i32x4 a;
#pragma unroll
    for (int r = 0; r < 4; ++r)
      a[r] = (int)((((bits >> (4 * r)) & 15u) * 0x00204081u) & 0x01010101u);

    const i32x4 z4 = {0, 0, 0, 0};
    i32x4 Slo, Shi, Cw;
    Slo = __builtin_amdgcn_mfma_i32_16x16x64_i8(a, B4L[lane],       z4, 0, 0, 0);
    Cw  = __builtin_amdgcn_mfma_i32_16x16x64_i8(a, B4L[64 + lane],  z4, 0, 0, 0);
    Slo += Cw << 8;
    Cw  = __builtin_amdgcn_mfma_i32_16x16x64_i8(a, B4L[128 + lane], z4, 0, 0, 0);
    Slo += Cw << 16;
    Shi = __builtin_amdgcn_mfma_i32_16x16x64_i8(a, B4L[192 + lane], z4, 0, 0, 0);
    Cw  = __builtin_amdgcn_mfma_i32_16x16x64_i8(a, B4L[256 + lane], z4, 0, 0, 0);
    Shi += Cw << 8;

    unsigned long long sel4 = 0ull;
#pragma unroll
    for (int r = 0; r < 4; ++r) {
      double md = fma(0.9, m4[r], -sv4[r]);
      md = fma((double)Slo[r], 0x1p-38, md);
      md = fma((double)Shi[r], 0x1p-14, md);
      m4[r] = md;
      const bool sp = md > 1.0;
      sv4[r] = sp ? 1.0 : 0.0;
      const unsigned long long b = __ballot(sp);
      sel4 = (r == 0) ? b : ((rsel == r) ? b : sel4);
    }
    const uint32_t msk4 = (uint32_t)(sel4 >> bshift) & 0xffffu;

    const uint32_t bits5 = (kg == 0) ? msk4 : 0u;
    i32x4 a5;
#pragma unroll
    for (int r = 0; r < 4; ++r)
      a5[r] = (int)((((bits5 >> (4 * r)) & 15u) * 0x00204081u) & 0x01010101u);

    Slo = __builtin_amdgcn_mfma_i32_16x16x64_i8(a5, B5L[lane],       z4, 0, 0, 0);
    Cw  = __builtin_amdgcn_mfma_i32_16x16x64_i8(a5, B5L[64 + lane],  z4, 0, 0, 0);
    Slo += Cw << 8;
    Cw  = __builtin_amdgcn_mfma_i32_16x16x64_i8(a5, B5L[128 + lane], z4, 0, 0, 0);
    Slo += Cw << 16;
    Shi = __builtin_amdgcn_mfma_i32_16x16x64_i8(a5, B5L[192 + lane], z4, 0, 0, 0);
    Cw  = __builtin_amdgcn_mfma_i32_16x16x64_i8(a5, B5L[256 + lane], z4, 0, 0, 0);
    Shi += Cw << 8;

    unsigned long long sel5 = 0ull;
#pragma unroll
    for (int r = 0; r < 4; ++r) {
      double md = fma(0.9, m5[r], -sv5[r]);
      md = fma((double)Slo[r], 0x1p-38, md);
      md = fma((double)Shi[r], 0x1p-14, md);
      m5[r] = md;
      const bool sp = md > 1.0;
      sv5[r] = sp ? 1.0 : 0.0;
      const unsigned long long b = __ballot(sp);
      sel5 = (r == 0) ? b : ((rsel == r) ? b : sel5);
    }
    if (lane < 16) {
      const uint32_t om6 = (uint32_t)(sel5 >> bshift) & 0x3fu;
      float* op = out + ((size_t)t * BB + ebase + el) * 6;
      ((float2*)op)[0] = make_float2((om6 & 1u)  ? 1.0f : 0.0f,
                                     (om6 & 2u)  ? 1.0f : 0.0f);
      ((float2*)op)[1] = make_float2((om6 & 4u)  ? 1.0f : 0.0f,
                                     (om6 & 8u)  ? 1.0f : 0.0f);
      ((float2*)op)[2] = make_float2((om6 & 16u) ? 1.0f : 0.0f,
                                     (om6 & 32u) ? 1.0f : 0.0f);
    }
  }
}

// ---------------- fallback: monolithic kernel (ws too small; f64 layout) ----------------

__global__ __launch_bounds__(256, 1) void snn_f64(const float* __restrict__ x,
                                                  const double* __restrict__ Wd,
                                                  float* __restrict__ out) {
  const int e = blockIdx.x * blockDim.x + threadIdx.x;

  double m1[64], m2[32], m3[32], m4[16], m5[6];
#pragma unroll
  for (int o = 0; o < 64; ++o) m1[o] = 0.0;
#pragma unroll
  for (int o = 0; o < 32; ++o) m2[o] = 0.0;
#pragma unroll
  for (int o = 0; o < 32; ++o) m3[o] = 0.0;
#pragma unroll
  for (int o = 0; o < 16; ++o) m4[o] = 0.0;
#pragma unroll
  for (int o = 0; o < 6; ++o) m5[o] = 0.0;

#pragma unroll 1
  for (int t = 0; t < TT; ++t) {
    const float* xp = x + ((size_t)t * BB + e) * 10;
    float xv[10];
#pragma unroll
    for (int i = 0; i < 5; ++i) {
      float2 f = ((const float2*)xp)[i];
      xv[2 * i] = f.x; xv[2 * i + 1] = f.y;
    }
#pragma unroll
    for (int o = 0; o < 64; ++o) {
      double sub = (m1[o] > 1.0) ? 1.0 : 0.0;
      m1[o] = 0.9 * m1[o] - sub;
    }
#pragma unroll
    for (int p = 0; p < 2; ++p) {
#pragma unroll
      for (int k = 0; k < 10; ++k) {
        double s = (double)xv[k];
        const double* col = Wd + p * 320 + k * 32;
#pragma unroll
        for (int o = 0; o < 32; ++o) m1[p * 32 + o] = fma(s, col[o], m1[p * 32 + o]);
      }
    }
    unsigned long long msk1 = 0ull;
#pragma unroll
    for (int o = 0; o < 64; ++o) msk1 |= (m1[o] > 1.0) ? (1ull << o) : 0ull;

#pragma unroll
    for (int o = 0; o < 32; ++o) {
      double sub = (m2[o] > 1.0) ? 1.0 : 0.0;
      m2[o] = 0.9 * m2[o] - sub;
    }
    {
      unsigned long long b = msk1;
      const double* col = Wd + OFF_W2T;
      for (int k = 0; k < 64; ++k) {
        double s = (double)(unsigned int)(b & 1ull);
        b >>= 1;
#pragma unroll
        for (int o = 0; o < 32; ++o) m2[o] = fma(s, col[o], m2[o]);
        col += 32;
      }
    }
    unsigned int msk2 = 0u;
#pragma unroll
    for (int o = 0; o < 32; ++o) msk2 |= (m2[o] > 1.0) ? (1u << o) : 0u;

#pragma unroll
    for (int o = 0; o < 32; ++o) {
      double sub = (m3[o] > 1.0) ? 1.0 : 0.0;
      m3[o] = 0.9 * m3[o] - sub;
    }
#pragma unroll
    for (int p = 0; p < 2; ++p) {
      unsigned int b = msk2;
      const double* col = Wd + OFF_W3P + p * 512;
      for (int k = 0; k < 32; ++k) {
        double s = (double)(b & 1u);
        b >>= 1;
#pragma unroll
        for (int o = 0; o < 16; ++o) m3[p * 16 + o] = fma(s, col[o], m3[p * 16 + o]);
        col += 16;
      }
    }
    unsigned int msk3 = 0u;
#pragma unroll
    for (int o = 0; o < 32; ++o) msk3 |= (m3[o] > 1.0) ? (1u << o) : 0u;

#pragma unroll
    for (int o = 0; o < 16; ++o) {
      double sub = (m4[o] > 1.0) ? 1.0 : 0.0;
      m4[o] = 0.9 * m4[o] - sub;
    }
    {
      unsigned int b = msk3;
      const double* col = Wd + OFF_W4T;
      for (int k = 0; k < 32; ++k) {
        double s = (double)(b & 1u);
        b >>= 1;
#pragma unroll
        for (int o = 0; o < 16; ++o) m4[o] = fma(s, col[o], m4[o]);
        col += 16;
      }
    }
    unsigned int msk4 = 0u;
#pragma unroll
    for (int o = 0; o < 16; ++o) msk4 |= (m4[o] > 1.0) ? (1u << o) : 0u;

#pragma unroll
    for (int o = 0; o < 6; ++o) {
      double sub = (m5[o] > 1.0) ? 1.0 : 0.0;
      m5[o] = 0.9 * m5[o] - sub;
    }
    {
      unsigned int b = msk4;
      const double* col = Wd + OFF_W5T;
      for (int k = 0; k < 16; ++k) {
        double s = (double)(b & 1u);
        b >>= 1;
#pragma unroll
        for (int o = 0; o < 6; ++o) m5[o] = fma(s, col[o], m5[o]);
        col += 6;
      }
    }

    float ov[6];
#pragma unroll
    for (int o = 0; o < 6; ++o) ov[o] = (m5[o] > 1.0) ? 1.0f : 0.0f;
    float* op = out + ((size_t)t * BB + e) * 6;
    ((float2*)op)[0] = make_float2(ov[0], ov[1]);
    ((float2*)op)[1] = make_float2(ov[2], ov[3]);
    ((float2*)op)[2] = make_float2(ov[4], ov[5]);
  }
}

extern "C" void kernel_launch(void* const* d_in, const int* in_sizes, int n_in,
                              void* d_out, int out_size, void* d_ws, size_t ws_size,
                              hipStream_t stream) {
  const float* x  = (const float*)d_in[0];
  const float* W1 = (const float*)d_in[1];
  const float* W2 = (const float*)d_in[2];
  const float* W3 = (const float*)d_in[3];
  const float* W4 = (const float*)d_in[4];
  const float* W5 = (const float*)d_in[5];
  float* out = (float*)d_out;
  double* Wd = (double*)d_ws;

  const int mode = (ws_size >= WS_NEEDED) ? 1 : 0;
  prep_weights<<<50, 256, 0, stream>>>(W1, W2, W3, W4, W5, Wd, mode);

  if (mode) {
    char* base = (char*)d_ws;
    uint32_t* P1 = (uint32_t*)(base + WS_MASK_BASE);   // u32[TT][BB][2]
    uint32_t* P2 = (uint32_t*)(base + P2_OFFSET);      // u32[TT][BB]
    uint32_t* P3 = (uint32_t*)(base + WS_MASK_BASE);   // u32[TT][BB], aliases P1
    const uint32_t* B1 = (const uint32_t*)(base + B1_OFFSET);  // tail of P2; dead once l2 runs
    snn_l1_mfma<<<2048, 256, 0, stream>>>(x, B1, P1);
    snn_l2_mfma<<<2048, 256, 0, stream>>>(Wd, P1, P2);
    snn_l3_mfma<<<2048, 256, 0, stream>>>(Wd, P2, P3);
    snn_l45_mfma<<<BB / 64, 256, 0, stream>>>(Wd, (const uint32_t*)P3, out);
  } else {
    snn_f64<<<BB / 256, 256, 0, stream>>>(x, Wd, out);
  }
}